// Round 1
// baseline (391.382 us; speedup 1.0000x reference)
//
#include <hip/hip_runtime.h>
#include <hip/hip_bf16.h>

// GAT-GAE forward: 2x GATConv + normalize + MLP decoder. fp32 I/O, int32 edges.
// Round 10: layer-1 aggregation hoisted past the GEMM (linearity):
//   agg1x gathers x (256B/edge, 12.8MB table) instead of h1 (512B/edge, 25.6MB)
//   and accumulates 4 head-weighted sums; gemm1b applies W1 afterwards via
//   MFMA (reuses W1f fragment packing: out-tile ng = h*4+nt). Layer-1 logits
//   via u-vectors u = W1 @ att (computed in w1f_k block 16, applied in xprep).
//   Edge weights fused into agg1x/agg2 -> ew1_k/ew2_k/row[] deleted.
//
// Workspace (bytes): W1f 64K | W2f 32K | u_s 2K | u_d 2K |
//   hxb u16[N*256] | xagg u16[N*512] | xb u16[N*128] | h2b u16[N*64] |
//   a_s1 f32[4N] | a_d1 f32[4N] | a_s2 f32[N] | a_d2 f32[N] |
//   rowptr int[N+1] | cursor int[N] | col int[Etot] | psum int[256]

#define IN_DIM   128
#define C1       256   // HEADS*HID
#define HEADS    4
#define HID      64
#define OUT_DIM  64

typedef __attribute__((ext_vector_type(8))) short short8;
typedef __attribute__((ext_vector_type(4))) float f32x4;

__device__ __forceinline__ float lrelu(float x) { return x > 0.f ? x : 0.2f * x; }
__device__ __forceinline__ float elu1(float x)  { return x > 0.f ? x : (__expf(x) - 1.f); }
__device__ __forceinline__ float expc(float x)  { return __expf(fminf(x, 60.f)); }
__device__ __forceinline__ float bfu(unsigned int u) {
    union { unsigned int i; float f; } c; c.i = u << 16; return c.f;
}
__device__ __forceinline__ unsigned short pk(float f) {
    union { float f; unsigned int i; } c; c.f = f;
    return (unsigned short)((c.i + 0x7fffu + ((c.i >> 16) & 1u)) >> 16);
}

// ============ weight prepack: B-fragment order for 16x16x32 bf16 ============
// Blocks 0..15: W1 [128][256] fp32 -> W1f[((nt*4+kc)*64 + lane)*8 + j] =
//   bf16(W1[(kc*32 + (lane>>4)*8 + j)*256 + nt*16 + (lane&15)])
// Block 16: u_s[h*128+k] = sum_c W1[k][h*64+c]*att_src1[h][c]; u_d likewise.
__global__ __launch_bounds__(256) void w1f_k(const float* __restrict__ W1,
                                             const float* __restrict__ as1,
                                             const float* __restrict__ ad1,
                                             unsigned short* __restrict__ W1f,
                                             float* __restrict__ u_s,
                                             float* __restrict__ u_d)
{
    if (blockIdx.x == 16) {
        for (int idx = threadIdx.x; idx < 512; idx += 256) {
            const int h = idx >> 7, k = idx & 127;
            float ss = 0.f, dd = 0.f;
            #pragma unroll 4
            for (int c = 0; c < 64; ++c) {
                const float wv = W1[k * 256 + h * 64 + c];
                ss += wv * as1[h * 64 + c];
                dd += wv * ad1[h * 64 + c];
            }
            u_s[idx] = ss;
            u_d[idx] = dd;
        }
        return;
    }
    const int idx = blockIdx.x * 256 + threadIdx.x;   // 4096 lane-entries
    if (idx >= 64 * 64) return;
    const int lane = idx & 63, e = idx >> 6;
    const int nt = e >> 2, kc = e & 3, q = lane >> 4, c = lane & 15;
    unsigned short tmp[8];
    #pragma unroll
    for (int j = 0; j < 8; ++j)
        tmp[j] = pk(W1[(kc * 32 + q * 8 + j) * 256 + nt * 16 + c]);
    ushort4* dst = (ushort4*)(W1f + (size_t)idx * 8);
    dst[0] = make_ushort4(tmp[0], tmp[1], tmp[2], tmp[3]);
    dst[1] = make_ushort4(tmp[4], tmp[5], tmp[6], tmp[7]);
}

// W2 [256][64] fp32 -> W2f[((nt*8+kc)*64 + lane)*8 + j]
__global__ __launch_bounds__(256) void w2f_k(const float* __restrict__ W2,
                                             unsigned short* __restrict__ W2f)
{
    const int idx = blockIdx.x * 256 + threadIdx.x;   // 2048 lane-entries
    if (idx >= 32 * 64) return;
    const int lane = idx & 63, e = idx >> 6;
    const int nt = e >> 3, kc = e & 7, q = lane >> 4, c = lane & 15;
    unsigned short tmp[8];
    #pragma unroll
    for (int j = 0; j < 8; ++j)
        tmp[j] = pk(W2[(kc * 32 + q * 8 + j) * 64 + nt * 16 + c]);
    ushort4* dst = (ushort4*)(W2f + (size_t)idx * 8);
    dst[0] = make_ushort4(tmp[0], tmp[1], tmp[2], tmp[3]);
    dst[1] = make_ushort4(tmp[4], tmp[5], tmp[6], tmp[7]);
}

// ============ xprep: cast x->bf16 + layer-1 logits via u-vectors ============
// 1 wave/node: lane l owns channels 2l,2l+1. a_s1[n,h] = x[n]·u_s[h].
__global__ __launch_bounds__(256) void xprep_k(
    const float* __restrict__ x, const float* __restrict__ u_s,
    const float* __restrict__ u_d, unsigned short* __restrict__ xb,
    float* __restrict__ a_s1, float* __restrict__ a_d1, int N)
{
    __shared__ float us[512], ud[512];
    const int t = threadIdx.x;
    for (int i = t; i < 512; i += 256) { us[i] = u_s[i]; ud[i] = u_d[i]; }
    __syncthreads();
    const int w = t >> 6, l = t & 63;
    const int n = blockIdx.x * 4 + w;
    if (n >= N) return;
    const float2 xv = *(const float2*)&x[(size_t)n * IN_DIM + 2 * l];
    const unsigned int p2 =
        (unsigned int)pk(xv.x) | ((unsigned int)pk(xv.y) << 16);
    *(unsigned int*)&xb[(size_t)n * IN_DIM + 2 * l] = p2;
    #pragma unroll
    for (int h = 0; h < 4; ++h) {
        float ps = xv.x * us[h * 128 + 2 * l] + xv.y * us[h * 128 + 2 * l + 1];
        float pd = xv.x * ud[h * 128 + 2 * l] + xv.y * ud[h * 128 + 2 * l + 1];
        #pragma unroll
        for (int off = 1; off < 64; off <<= 1) {
            ps += __shfl_xor(ps, off, 64);
            pd += __shfl_xor(pd, off, 64);
        }
        if (l == 0) {
            a_s1[n * 4 + h] = ps;
            a_d1[n * 4 + h] = pd;
        }
    }
}

// ================= CSR build =================
__global__ void deg_k(const int* __restrict__ ei, int E, int Etot,
                      int* __restrict__ rowptr)
{
    const int e = blockIdx.x * blockDim.x + threadIdx.x;
    if (e >= Etot) return;
    const int d = (e < E) ? ei[E + e] : e - E;
    atomicAdd(&rowptr[1 + d], 1);
}

__device__ __forceinline__ int blk_incl_scan(int v, int t) {
    __shared__ int wsum[4];
    const int lane = t & 63, wid = t >> 6;
    int s = v;
    #pragma unroll
    for (int off = 1; off < 64; off <<= 1) {
        const int u = __shfl_up(s, off, 64);
        if (lane >= off) s += u;
    }
    if (lane == 63) wsum[wid] = s;
    __syncthreads();
    int add = 0;
    #pragma unroll
    for (int k = 0; k < 4; ++k) if (k < wid) add += wsum[k];
    __syncthreads();
    return s + add;
}

__global__ __launch_bounds__(256) void scanA_k(const int* __restrict__ rowptr,
                                               int* __restrict__ psum, int N)
{
    const int t = threadIdx.x;
    const int i = blockIdx.x * 256 + t;
    int v = (i < N) ? rowptr[1 + i] : 0;
    #pragma unroll
    for (int off = 1; off < 64; off <<= 1) v += __shfl_xor(v, off, 64);
    __shared__ int ws[4];
    if ((t & 63) == 0) ws[t >> 6] = v;
    __syncthreads();
    if (t == 0) psum[blockIdx.x] = ws[0] + ws[1] + ws[2] + ws[3];
}

__global__ __launch_bounds__(256) void scanB_k(int* __restrict__ psum, int SC)
{
    const int t = threadIdx.x;
    const int v = (t < SC) ? psum[t] : 0;
    const int inc = blk_incl_scan(v, t);
    if (t < SC) psum[t] = inc - v;   // exclusive
}

__global__ __launch_bounds__(256) void scanC_k(int* __restrict__ rowptr,
                                               int* __restrict__ cursor,
                                               const int* __restrict__ psum, int N)
{
    const int t = threadIdx.x;
    const int i = blockIdx.x * 256 + t;
    const int v = (i < N) ? rowptr[1 + i] : 0;
    const int inc = blk_incl_scan(v, t);
    const int base = psum[blockIdx.x];
    if (i < N) {
        rowptr[1 + i] = base + inc;
        cursor[i]     = base + inc - v;
    }
}

__global__ void fill_k(const int* __restrict__ ei, int E, int Etot,
                       int* __restrict__ cursor, int* __restrict__ col)
{
    const int e = blockIdx.x * blockDim.x + threadIdx.x;
    if (e >= Etot) return;
    int s, d;
    if (e < E) { s = ei[e]; d = ei[E + e]; } else { s = d = e - E; }
    const int pos = atomicAdd(&cursor[d], 1);
    col[pos] = s;
}

// ====== Layer-1 aggregate over x: xagg[n,h,:] = (sum_e w_e^h x[src]) / sum w ==
// 1 wave/node. Lane l: channels (2l,2l+1) for ALL heads; weight duty:
// (head = l>>4, edge = l&15) within each 16-edge chunk. Fused edge weights
// from L2-resident a_s1/a_d1 tables. Gather = 256B/edge from 12.8MB table.
__global__ __launch_bounds__(256) void agg1x_k(
    const int* __restrict__ rowptr, const int* __restrict__ col,
    const float* __restrict__ a_s1, const float* __restrict__ a_d1,
    const unsigned short* __restrict__ xb, unsigned short* __restrict__ xagg,
    int N)
{
    const int t = threadIdx.x, w = t >> 6, l = t & 63;
    const int n = blockIdx.x * 4 + w;
    if (n >= N) return;
    const int beg = rowptr[n], end = rowptr[n + 1];
    const int head = l >> 4, e16 = l & 15;
    const float dv = a_d1[n * 4 + head];
    float acc[4][2] = {{0.f,0.f},{0.f,0.f},{0.f,0.f},{0.f,0.f}};
    float wsum = 0.f;
    for (int t0 = beg; t0 < end; t0 += 16) {
        const int m = min(16, end - t0);
        const int pe = t0 + e16;
        const int   scol = (pe < end) ? col[pe] : 0;
        const float sv   = (pe < end) ? a_s1[scol * 4 + head] : 0.f;
        const float wst  = (pe < end) ? expc(lrelu(sv + dv)) : 0.f;
        wsum += wst;
        for (int j0 = 0; j0 < m; j0 += 8) {
            unsigned int hv[8];
            #pragma unroll
            for (int u = 0; u < 8; ++u) {                 // 8 gathers in flight
                const int su = __shfl(scol, j0 + u, 64);
                hv[u] = *(const unsigned int*)(xb + (size_t)su * IN_DIM + 2 * l);
            }
            #pragma unroll
            for (int u = 0; u < 8; ++u) {
                const float x0 = bfu(hv[u] & 0xffffu);
                const float x1 = bfu(hv[u] >> 16);
                #pragma unroll
                for (int h = 0; h < 4; ++h) {
                    const float ww = __shfl(wst, h * 16 + j0 + u, 64);
                    acc[h][0] = fmaf(x0, ww, acc[h][0]);
                    acc[h][1] = fmaf(x1, ww, acc[h][1]);
                }
            }
        }
    }
    #pragma unroll
    for (int off = 1; off < 16; off <<= 1) wsum += __shfl_xor(wsum, off, 64);
    const float inv = 1.f / (wsum + 1e-16f);
    float ih[4];
    #pragma unroll
    for (int h = 0; h < 4; ++h) ih[h] = __shfl(inv, h * 16, 64);
    #pragma unroll
    for (int h = 0; h < 4; ++h) {
        const unsigned int o =
            (unsigned int)pk(acc[h][0] * ih[h]) |
            ((unsigned int)pk(acc[h][1] * ih[h]) << 16);
        *(unsigned int*)&xagg[(size_t)n * 512 + h * 128 + 2 * l] = o;
    }
}

// ==== Layer-1 GEMM (post-agg, MFMA): hx = elu(xagg @ W1 + b1), block-diag ===
// xagg row = [h*128 + k]. Out col h*64+nt*16+c -> W1f tile ng = h*4+nt (same
// packing as before). Two N-halves share one 33KB LDS stage buffer.
__global__ __launch_bounds__(256) void gemm1b_k(
    const unsigned short* __restrict__ xagg, const unsigned short* __restrict__ W1f,
    const float* __restrict__ b1, unsigned short* __restrict__ hxb, int N)
{
    __shared__ short lds[64 * 264];
    const int t = threadIdx.x, w = t >> 6, l = t & 63;
    const int q = l >> 4, c = l & 15;
    const int n0 = blockIdx.x * 64;
    const int arow = 16 * w + c;
    f32x4 acc[16];
    #pragma unroll
    for (int nt = 0; nt < 16; ++nt) acc[nt] = (f32x4){0.f, 0.f, 0.f, 0.f};
    #pragma unroll
    for (int half = 0; half < 2; ++half) {
        if (half) __syncthreads();           // protect LDS reuse
        for (int i = t; i < 64 * 32; i += 256) {
            const int r = i >> 5, ch = (i & 31) * 8;
            const int rn = min(n0 + r, N - 1);
            *(short8*)&lds[r * 264 + ch] =
                *(const short8*)&xagg[(size_t)rn * 512 + half * 256 + ch];
        }
        __syncthreads();
        #pragma unroll
        for (int hh = 0; hh < 2; ++hh) {
            const int h = half * 2 + hh;
            short8 afr[4];
            #pragma unroll
            for (int kc = 0; kc < 4; ++kc)
                afr[kc] = *(const short8*)&lds[arow * 264 + hh * 128 + kc * 32 + q * 8];
            #pragma unroll
            for (int nt = 0; nt < 4; ++nt) {
                #pragma unroll
                for (int kc = 0; kc < 4; ++kc) {
                    const short8 bfr = *(const short8*)(W1f +
                        ((size_t)((h * 4 + nt) * 4 + kc) * 64 + l) * 8);
                    acc[h * 4 + nt] = __builtin_amdgcn_mfma_f32_16x16x32_bf16(
                        afr[kc], bfr, acc[h * 4 + nt], 0, 0, 0);
                }
            }
        }
    }
    __syncthreads();
    #pragma unroll
    for (int nt = 0; nt < 16; ++nt)
        #pragma unroll
        for (int r = 0; r < 4; ++r) {
            const float v = elu1(acc[nt][r] + b1[nt * 16 + c]);
            lds[(16 * w + q * 4 + r) * 264 + nt * 16 + c] = (short)pk(v);
        }
    __syncthreads();
    for (int i = t; i < 64 * 32; i += 256) {
        const int r = i >> 5, ch = (i & 31) * 8;
        const int node = n0 + r;
        if (node < N)
            *(short8*)&hxb[(size_t)node * C1 + ch] =
                *(const short8*)&lds[r * 264 + ch];
    }
}

// ============ Layer-2 GEMM (MFMA): h2 = hx @ W2 (bf16) + logits =============
__global__ __launch_bounds__(256) void gemm2_k(
    const unsigned short* __restrict__ hxb, const unsigned short* __restrict__ W2f,
    const float* __restrict__ as2, const float* __restrict__ ad2,
    unsigned short* __restrict__ h2b, float* __restrict__ a_s2,
    float* __restrict__ a_d2, int N)
{
    __shared__ short lds[64 * 264];   // stage: [row][264] (K=256+pad8)
    const int t = threadIdx.x, w = t >> 6, l = t & 63;
    const int q = l >> 4, c = l & 15;
    const int n0 = blockIdx.x * 64;
    for (int i = t; i < 64 * 32; i += 256) {
        const int r = i >> 5, ch = (i & 31) * 8;
        const int rn = min(n0 + r, N - 1);
        *(short8*)&lds[r * 264 + ch] =
            *(const short8*)&hxb[(size_t)rn * C1 + ch];
    }
    __syncthreads();
    short8 afr[8];
    const int arow = 16 * w + c;
    #pragma unroll
    for (int kc = 0; kc < 8; ++kc)
        afr[kc] = *(const short8*)&lds[arow * 264 + kc * 32 + q * 8];
    f32x4 acc[4];
    #pragma unroll
    for (int nt = 0; nt < 4; ++nt) acc[nt] = (f32x4){0.f, 0.f, 0.f, 0.f};
    #pragma unroll
    for (int nt = 0; nt < 4; ++nt) {
        #pragma unroll
        for (int kc = 0; kc < 8; ++kc) {
            const short8 bfr =
                *(const short8*)(W2f + ((size_t)(nt * 8 + kc) * 64 + l) * 8);
            acc[nt] = __builtin_amdgcn_mfma_f32_16x16x32_bf16(afr[kc], bfr,
                                                              acc[nt], 0, 0, 0);
        }
    }
    // logits (single head over all 64 cols)
    {
        float vsr[4] = {0.f, 0.f, 0.f, 0.f}, vdr[4] = {0.f, 0.f, 0.f, 0.f};
        #pragma unroll
        for (int nt = 0; nt < 4; ++nt) {
            const float sa = as2[nt * 16 + c], da = ad2[nt * 16 + c];
            #pragma unroll
            for (int r = 0; r < 4; ++r) {
                vsr[r] += acc[nt][r] * sa;
                vdr[r] += acc[nt][r] * da;
            }
        }
        #pragma unroll
        for (int r = 0; r < 4; ++r) {
            #pragma unroll
            for (int off = 1; off < 16; off <<= 1) {
                vsr[r] += __shfl_xor(vsr[r], off, 64);
                vdr[r] += __shfl_xor(vdr[r], off, 64);
            }
            const int node = n0 + 16 * w + q * 4 + r;
            if (c == 0 && node < N) {
                a_s2[node] = vsr[r];
                a_d2[node] = vdr[r];
            }
        }
    }
    __syncthreads();
    #pragma unroll
    for (int nt = 0; nt < 4; ++nt)
        #pragma unroll
        for (int r = 0; r < 4; ++r)
            lds[(16 * w + q * 4 + r) * 72 + nt * 16 + c] = (short)pk(acc[nt][r]);
    __syncthreads();
    for (int i = t; i < 64 * 8; i += 256) {
        const int r = i >> 3, ch = (i & 7) * 8;
        const int node = n0 + r;
        if (node < N)
            *(short8*)&h2b[(size_t)node * OUT_DIM + ch] =
                *(const short8*)&lds[r * 72 + ch];
    }
}

// ====== Layer-2 aggregate: 1 wave/node, lane = 2 ch; fused edge weights =====
__global__ __launch_bounds__(256) void agg2_k(
    const int* __restrict__ rowptr, const int* __restrict__ col,
    const float* __restrict__ a_s2, const float* __restrict__ a_d2,
    const unsigned short* __restrict__ h2b, const float* __restrict__ b2,
    float* __restrict__ zout, int N)
{
    const int t = threadIdx.x, w = t >> 6, l = t & 63;
    const int n = blockIdx.x * 4 + w;
    if (n >= N) return;
    const int beg = rowptr[n], end = rowptr[n + 1];
    const float dn = a_d2[n];
    const int half = l >> 5, c2 = l & 31;     // lane owns ch 2*c2, 2*c2+1
    float a0 = 0.f, a1 = 0.f, wsum = 0.f;
    for (int t0 = beg; t0 < end; t0 += 64) {
        const int m = min(64, end - t0);
        const int p = t0 + l;
        const int   scol = (p < end) ? col[p] : 0;
        const float wv   = (p < end) ? expc(lrelu(a_s2[scol] + dn)) : 0.f;
        const int pairs = (m + 1) >> 1;
        for (int j0 = 0; j0 < pairs; j0 += 8) {
            unsigned int hv[8]; float wu[8];
            #pragma unroll
            for (int u = 0; u < 8; ++u) {
                const int e = 2 * (j0 + u) + half;        // <= 63 always
                const int su = __shfl(scol, e, 64);
                wu[u] = __shfl(wv, e, 64);
                hv[u] = *(const unsigned int*)(h2b + (size_t)su * OUT_DIM + 2 * c2);
            }
            #pragma unroll
            for (int u = 0; u < 8; ++u) {
                a0 = fmaf(bfu(hv[u] & 0xffffu), wu[u], a0);
                a1 = fmaf(bfu(hv[u] >> 16), wu[u], a1);
                wsum += wu[u];
            }
        }
    }
    a0   += __shfl_xor(a0, 32, 64);
    a1   += __shfl_xor(a1, 32, 64);
    wsum += __shfl_xor(wsum, 32, 64);
    const float inv = 1.f / (wsum + 1e-16f);
    float z0 = a0 * inv + b2[2 * c2];
    float z1 = a1 * inv + b2[2 * c2 + 1];
    float sq = z0 * z0 + z1 * z1;
    #pragma unroll
    for (int off = 1; off < 32; off <<= 1) sq += __shfl_xor(sq, off, 64);
    const float rn = 1.f / fmaxf(sqrtf(sq), 1e-12f);
    if (l < 32) {
        float2 o; o.x = z0 * rn; o.y = z1 * rn;
        *(float2*)&zout[(size_t)n * OUT_DIM + 2 * c2] = o;
    }
}

// ================= Decoder: x_hat = elu(z@dW1+db1)@dW2+db2 =================
__global__ __launch_bounds__(256) void dec_k(
    const float* __restrict__ z,
    const float* __restrict__ dW1, const float* __restrict__ db1,
    const float* __restrict__ dW2, const float* __restrict__ db2,
    float* __restrict__ xhat, int N)
{
    __shared__ float zs[32 * 64];
    __shared__ float ts[32 * 64];
    const int t = threadIdx.x;
    const int n0 = blockIdx.x * 32;
    for (int i = t; i < 32 * 64; i += 256) {
        const int nb_l = i >> 6, k = i & 63;
        const int n = min(n0 + nb_l, N - 1);
        zs[(nb_l >> 3) * 512 + k * 8 + (nb_l & 7)] = z[(size_t)n * OUT_DIM + k];
    }
    __syncthreads();
    const int w = t >> 6, l = t & 63;
    const float* zw = zs + w * 512;
    float* tw = ts + w * 512;
    float acc[8] = {0.f, 0.f, 0.f, 0.f, 0.f, 0.f, 0.f, 0.f};
    #pragma unroll 4
    for (int k = 0; k < 64; ++k) {
        const float wv = dW1[k * HID + l];
        const float4 xa = *(const float4*)&zw[k * 8];
        const float4 xb = *(const float4*)&zw[k * 8 + 4];
        acc[0] += xa.x * wv; acc[1] += xa.y * wv;
        acc[2] += xa.z * wv; acc[3] += xa.w * wv;
        acc[4] += xb.x * wv; acc[5] += xb.y * wv;
        acc[6] += xb.z * wv; acc[7] += xb.w * wv;
    }
    const float bb = db1[l];
    #pragma unroll
    for (int nb = 0; nb < 8; ++nb) tw[l * 8 + nb] = elu1(acc[nb] + bb);
    __syncthreads();
    float a0[8] = {0.f, 0.f, 0.f, 0.f, 0.f, 0.f, 0.f, 0.f};
    float a1[8] = {0.f, 0.f, 0.f, 0.f, 0.f, 0.f, 0.f, 0.f};
    #pragma unroll 2
    for (int k = 0; k < 64; ++k) {
        const float w0 = dW2[k * IN_DIM + l];
        const float w1 = dW2[k * IN_DIM + 64 + l];
        const float4 xa = *(const float4*)&tw[k * 8];
        const float4 xb = *(const float4*)&tw[k * 8 + 4];
        const float xv[8] = {xa.x, xa.y, xa.z, xa.w, xb.x, xb.y, xb.z, xb.w};
        #pragma unroll
        for (int nb = 0; nb < 8; ++nb) {
            a0[nb] += xv[nb] * w0;
            a1[nb] += xv[nb] * w1;
        }
    }
    const float bb0 = db2[l], bb1 = db2[64 + l];
    #pragma unroll
    for (int nb = 0; nb < 8; ++nb) {
        const int n = n0 + w * 8 + nb;
        if (n >= N) break;
        xhat[(size_t)n * IN_DIM + l]      = a0[nb] + bb0;
        xhat[(size_t)n * IN_DIM + 64 + l] = a1[nb] + bb1;
    }
}

extern "C" void kernel_launch(void* const* d_in, const int* in_sizes, int n_in,
                              void* d_out, int out_size, void* d_ws, size_t ws_size,
                              hipStream_t stream)
{
    const float* x   = (const float*)d_in[0];
    const int*   ei  = (const int*)d_in[1];
    const float* W1  = (const float*)d_in[2];
    const float* as1 = (const float*)d_in[3];
    const float* ad1 = (const float*)d_in[4];
    const float* b1  = (const float*)d_in[5];
    const float* W2  = (const float*)d_in[6];
    const float* as2 = (const float*)d_in[7];
    const float* ad2 = (const float*)d_in[8];
    const float* b2  = (const float*)d_in[9];
    const float* dW1 = (const float*)d_in[10];
    const float* db1 = (const float*)d_in[11];
    const float* dW2 = (const float*)d_in[12];
    const float* db2 = (const float*)d_in[13];

    const int N    = in_sizes[0] / IN_DIM;
    const int E    = in_sizes[1] / 2;
    const int Etot = E + N;

    // fixed-size region first (keeps every u16 array 16B-aligned for any N)
    unsigned short* W1f = (unsigned short*)d_ws;           // 32768 u16
    unsigned short* W2f = W1f + 32768;                     // 16384 u16
    float* u_s = (float*)(W2f + 16384);                    // 512 f32
    float* u_d = u_s + 512;                                // 512 f32
    unsigned short* hxb  = (unsigned short*)(u_d + 512);   // N*256 u16
    unsigned short* xagg = hxb  + (size_t)N * C1;          // N*512 u16
    unsigned short* xb   = xagg + (size_t)N * 512;         // N*128 u16
    unsigned short* h2b  = xb   + (size_t)N * IN_DIM;      // N*64  u16
    float* a_s1 = (float*)(h2b + (size_t)N * OUT_DIM);     // N*4
    float* a_d1 = a_s1 + (size_t)N * HEADS;                // N*4
    float* a_s2 = a_d1 + (size_t)N * HEADS;                // N
    float* a_d2 = a_s2 + (size_t)N;                        // N
    int* rowptr = (int*)(a_d2 + (size_t)N);                // N+1
    int* cursor = rowptr + (N + 1);                        // N
    int* col    = cursor + N;                              // Etot
    int* psum   = col + Etot;                              // 256

    const size_t needed = (size_t)N * 1968 + (size_t)Etot * 4 + 103428;
    if (ws_size < needed) return;  // loud failure signature

    hipMemsetAsync(rowptr, 0, (size_t)(N + 1) * sizeof(int), stream);

    const int eblk  = (Etot + 255) / 256;
    const int SC    = (N + 255) / 256;           // <=256 chunks (N=50k -> 196)
    const int mblk  = (N + 63) / 64;
    const int nblk4 = (N + 3) / 4;
    w1f_k   <<<17, 256, 0, stream>>>(W1, as1, ad1, W1f, u_s, u_d);
    w2f_k   <<<8, 256, 0, stream>>>(W2, W2f);
    xprep_k <<<nblk4, 256, 0, stream>>>(x, u_s, u_d, xb, a_s1, a_d1, N);
    deg_k   <<<eblk, 256, 0, stream>>>(ei, E, Etot, rowptr);
    scanA_k <<<SC, 256, 0, stream>>>(rowptr, psum, N);
    scanB_k <<<1, 256, 0, stream>>>(psum, SC);
    scanC_k <<<SC, 256, 0, stream>>>(rowptr, cursor, psum, N);
    fill_k  <<<eblk, 256, 0, stream>>>(ei, E, Etot, cursor, col);
    agg1x_k <<<nblk4, 256, 0, stream>>>(rowptr, col, a_s1, a_d1, xb, xagg, N);
    gemm1b_k<<<mblk, 256, 0, stream>>>(xagg, W1f, b1, hxb, N);
    gemm2_k <<<mblk, 256, 0, stream>>>(hxb, W2f, as2, ad2, h2b, a_s2, a_d2, N);
    agg2_k  <<<nblk4, 256, 0, stream>>>(rowptr, col, a_s2, a_d2, h2b, b2,
                                        (float*)d_out, N);
    dec_k   <<<(N + 31) / 32, 256, 0, stream>>>((const float*)d_out, dW1, db1,
                                                dW2, db2,
                                                (float*)d_out + (size_t)N * OUT_DIM, N);
}

// Round 2
// 375.735 us; speedup vs baseline: 1.0416x; 1.0416x over previous
//
#include <hip/hip_runtime.h>
#include <hip/hip_bf16.h>

// GAT-GAE forward: 2x GATConv + normalize + MLP decoder. fp32 I/O, int32 edges.
// Round 11: aggregation inner loops de-shfl'd. Per 64-edge chunk, each lane
// stages its edge's {scol, weight(s)} into per-wave LDS scratch; the consume
// loop reads them back with uniform-address ds_read (broadcast, no bpermute),
// so the 8 gathers issue with no cross-lane dependency chain in front.
//   agg1x: 5 shfl/edge -> ~1.3 ds_read/edge (scol via int4, w4 via b128)
//   agg2:  2 shfl/edge -> 0.5 ds_read_b64/edge (packed {scol,w})
// wsum accumulated at staging time (per-lane partial + one final butterfly).
//
// Workspace (bytes): W1f 64K | W2f 32K | u_s 2K | u_d 2K |
//   hxb u16[N*256] | xagg u16[N*512] | xb u16[N*128] | h2b u16[N*64] |
//   a_s1 f32[4N] | a_d1 f32[4N] | a_s2 f32[N] | a_d2 f32[N] |
//   rowptr int[N+1] | cursor int[N] | col int[Etot] | psum int[256]

#define IN_DIM   128
#define C1       256   // HEADS*HID
#define HEADS    4
#define HID      64
#define OUT_DIM  64

typedef __attribute__((ext_vector_type(8))) short short8;
typedef __attribute__((ext_vector_type(4))) float f32x4;

__device__ __forceinline__ float lrelu(float x) { return x > 0.f ? x : 0.2f * x; }
__device__ __forceinline__ float elu1(float x)  { return x > 0.f ? x : (__expf(x) - 1.f); }
__device__ __forceinline__ float expc(float x)  { return __expf(fminf(x, 60.f)); }
__device__ __forceinline__ float bfu(unsigned int u) {
    union { unsigned int i; float f; } c; c.i = u << 16; return c.f;
}
__device__ __forceinline__ unsigned short pk(float f) {
    union { float f; unsigned int i; } c; c.f = f;
    return (unsigned short)((c.i + 0x7fffu + ((c.i >> 16) & 1u)) >> 16);
}

// ============ weight prepack: B-fragment order for 16x16x32 bf16 ============
// Blocks 0..15: W1 [128][256] fp32 -> W1f[((nt*4+kc)*64 + lane)*8 + j] =
//   bf16(W1[(kc*32 + (lane>>4)*8 + j)*256 + nt*16 + (lane&15)])
// Block 16: u_s[h*128+k] = sum_c W1[k][h*64+c]*att_src1[h][c]; u_d likewise.
__global__ __launch_bounds__(256) void w1f_k(const float* __restrict__ W1,
                                             const float* __restrict__ as1,
                                             const float* __restrict__ ad1,
                                             unsigned short* __restrict__ W1f,
                                             float* __restrict__ u_s,
                                             float* __restrict__ u_d)
{
    if (blockIdx.x == 16) {
        for (int idx = threadIdx.x; idx < 512; idx += 256) {
            const int h = idx >> 7, k = idx & 127;
            float ss = 0.f, dd = 0.f;
            #pragma unroll 4
            for (int c = 0; c < 64; ++c) {
                const float wv = W1[k * 256 + h * 64 + c];
                ss += wv * as1[h * 64 + c];
                dd += wv * ad1[h * 64 + c];
            }
            u_s[idx] = ss;
            u_d[idx] = dd;
        }
        return;
    }
    const int idx = blockIdx.x * 256 + threadIdx.x;   // 4096 lane-entries
    if (idx >= 64 * 64) return;
    const int lane = idx & 63, e = idx >> 6;
    const int nt = e >> 2, kc = e & 3, q = lane >> 4, c = lane & 15;
    unsigned short tmp[8];
    #pragma unroll
    for (int j = 0; j < 8; ++j)
        tmp[j] = pk(W1[(kc * 32 + q * 8 + j) * 256 + nt * 16 + c]);
    ushort4* dst = (ushort4*)(W1f + (size_t)idx * 8);
    dst[0] = make_ushort4(tmp[0], tmp[1], tmp[2], tmp[3]);
    dst[1] = make_ushort4(tmp[4], tmp[5], tmp[6], tmp[7]);
}

// W2 [256][64] fp32 -> W2f[((nt*8+kc)*64 + lane)*8 + j]
__global__ __launch_bounds__(256) void w2f_k(const float* __restrict__ W2,
                                             unsigned short* __restrict__ W2f)
{
    const int idx = blockIdx.x * 256 + threadIdx.x;   // 2048 lane-entries
    if (idx >= 32 * 64) return;
    const int lane = idx & 63, e = idx >> 6;
    const int nt = e >> 3, kc = e & 7, q = lane >> 4, c = lane & 15;
    unsigned short tmp[8];
    #pragma unroll
    for (int j = 0; j < 8; ++j)
        tmp[j] = pk(W2[(kc * 32 + q * 8 + j) * 64 + nt * 16 + c]);
    ushort4* dst = (ushort4*)(W2f + (size_t)idx * 8);
    dst[0] = make_ushort4(tmp[0], tmp[1], tmp[2], tmp[3]);
    dst[1] = make_ushort4(tmp[4], tmp[5], tmp[6], tmp[7]);
}

// ============ xprep: cast x->bf16 + layer-1 logits via u-vectors ============
// 1 wave/node: lane l owns channels 2l,2l+1. a_s1[n,h] = x[n]·u_s[h].
__global__ __launch_bounds__(256) void xprep_k(
    const float* __restrict__ x, const float* __restrict__ u_s,
    const float* __restrict__ u_d, unsigned short* __restrict__ xb,
    float* __restrict__ a_s1, float* __restrict__ a_d1, int N)
{
    __shared__ float us[512], ud[512];
    const int t = threadIdx.x;
    for (int i = t; i < 512; i += 256) { us[i] = u_s[i]; ud[i] = u_d[i]; }
    __syncthreads();
    const int w = t >> 6, l = t & 63;
    const int n = blockIdx.x * 4 + w;
    if (n >= N) return;
    const float2 xv = *(const float2*)&x[(size_t)n * IN_DIM + 2 * l];
    const unsigned int p2 =
        (unsigned int)pk(xv.x) | ((unsigned int)pk(xv.y) << 16);
    *(unsigned int*)&xb[(size_t)n * IN_DIM + 2 * l] = p2;
    #pragma unroll
    for (int h = 0; h < 4; ++h) {
        float ps = xv.x * us[h * 128 + 2 * l] + xv.y * us[h * 128 + 2 * l + 1];
        float pd = xv.x * ud[h * 128 + 2 * l] + xv.y * ud[h * 128 + 2 * l + 1];
        #pragma unroll
        for (int off = 1; off < 64; off <<= 1) {
            ps += __shfl_xor(ps, off, 64);
            pd += __shfl_xor(pd, off, 64);
        }
        if (l == 0) {
            a_s1[n * 4 + h] = ps;
            a_d1[n * 4 + h] = pd;
        }
    }
}

// ================= CSR build =================
__global__ void deg_k(const int* __restrict__ ei, int E, int Etot,
                      int* __restrict__ rowptr)
{
    const int e = blockIdx.x * blockDim.x + threadIdx.x;
    if (e >= Etot) return;
    const int d = (e < E) ? ei[E + e] : e - E;
    atomicAdd(&rowptr[1 + d], 1);
}

__device__ __forceinline__ int blk_incl_scan(int v, int t) {
    __shared__ int wsum[4];
    const int lane = t & 63, wid = t >> 6;
    int s = v;
    #pragma unroll
    for (int off = 1; off < 64; off <<= 1) {
        const int u = __shfl_up(s, off, 64);
        if (lane >= off) s += u;
    }
    if (lane == 63) wsum[wid] = s;
    __syncthreads();
    int add = 0;
    #pragma unroll
    for (int k = 0; k < 4; ++k) if (k < wid) add += wsum[k];
    __syncthreads();
    return s + add;
}

__global__ __launch_bounds__(256) void scanA_k(const int* __restrict__ rowptr,
                                               int* __restrict__ psum, int N)
{
    const int t = threadIdx.x;
    const int i = blockIdx.x * 256 + t;
    int v = (i < N) ? rowptr[1 + i] : 0;
    #pragma unroll
    for (int off = 1; off < 64; off <<= 1) v += __shfl_xor(v, off, 64);
    __shared__ int ws[4];
    if ((t & 63) == 0) ws[t >> 6] = v;
    __syncthreads();
    if (t == 0) psum[blockIdx.x] = ws[0] + ws[1] + ws[2] + ws[3];
}

__global__ __launch_bounds__(256) void scanB_k(int* __restrict__ psum, int SC)
{
    const int t = threadIdx.x;
    const int v = (t < SC) ? psum[t] : 0;
    const int inc = blk_incl_scan(v, t);
    if (t < SC) psum[t] = inc - v;   // exclusive
}

__global__ __launch_bounds__(256) void scanC_k(int* __restrict__ rowptr,
                                               int* __restrict__ cursor,
                                               const int* __restrict__ psum, int N)
{
    const int t = threadIdx.x;
    const int i = blockIdx.x * 256 + t;
    const int v = (i < N) ? rowptr[1 + i] : 0;
    const int inc = blk_incl_scan(v, t);
    const int base = psum[blockIdx.x];
    if (i < N) {
        rowptr[1 + i] = base + inc;
        cursor[i]     = base + inc - v;
    }
}

__global__ void fill_k(const int* __restrict__ ei, int E, int Etot,
                       int* __restrict__ cursor, int* __restrict__ col)
{
    const int e = blockIdx.x * blockDim.x + threadIdx.x;
    if (e >= Etot) return;
    int s, d;
    if (e < E) { s = ei[e]; d = ei[E + e]; } else { s = d = e - E; }
    const int pos = atomicAdd(&cursor[d], 1);
    col[pos] = s;
}

// ====== Layer-1 aggregate over x: xagg[n,h,:] = (sum_e w_e^h x[src]) / sum w ==
// 1 wave/node; lane l owns channels (2l,2l+1) for all 4 heads.
// Per 64-edge chunk: lane l stages edge (t0+l)'s {scol, float4 weights} into
// per-wave LDS; consume loop reads them via uniform ds_read (broadcast) so
// the 8-deep gather batch has no shfl chain in front of its addresses.
// Tail lanes stage {0, 0-weights}: rounded-up batches gather node 0 (L1 hit)
// with zero weight -- harmless.
__global__ __launch_bounds__(256) void agg1x_k(
    const int* __restrict__ rowptr, const int* __restrict__ col,
    const float* __restrict__ a_s1, const float* __restrict__ a_d1,
    const unsigned short* __restrict__ xb, unsigned short* __restrict__ xagg,
    int N)
{
    __shared__ int    scolS[4][64];
    __shared__ float4 w4S[4][64];
    const int t = threadIdx.x, w = t >> 6, l = t & 63;
    const int n = blockIdx.x * 4 + w;
    if (n >= N) return;
    const int beg = rowptr[n], end = rowptr[n + 1];
    const float4 dv = *(const float4*)&a_d1[n * 4];
    float4 ws = {0.f, 0.f, 0.f, 0.f};
    float acc[4][2] = {{0.f,0.f},{0.f,0.f},{0.f,0.f},{0.f,0.f}};
    for (int t0 = beg; t0 < end; t0 += 64) {
        const int m = min(64, end - t0);
        const int p = t0 + l;
        int sc = 0;
        float4 wv = {0.f, 0.f, 0.f, 0.f};
        if (p < end) {
            sc = col[p];
            const float4 av = *(const float4*)&a_s1[sc * 4];
            wv.x = expc(lrelu(av.x + dv.x));
            wv.y = expc(lrelu(av.y + dv.y));
            wv.z = expc(lrelu(av.z + dv.z));
            wv.w = expc(lrelu(av.w + dv.w));
            ws.x += wv.x; ws.y += wv.y; ws.z += wv.z; ws.w += wv.w;
        }
        scolS[w][l] = sc;
        w4S[w][l]   = wv;
        __threadfence_block();           // within-wave LDS write->read order
        for (int j0 = 0; j0 < m; j0 += 8) {
            const int4 s0 = *(const int4*)&scolS[w][j0];
            const int4 s1 = *(const int4*)&scolS[w][j0 + 4];
            const int su[8] = {s0.x, s0.y, s0.z, s0.w, s1.x, s1.y, s1.z, s1.w};
            unsigned int hv[8];
            #pragma unroll
            for (int u = 0; u < 8; ++u)   // 8 gathers in flight
                hv[u] = *(const unsigned int*)(xb + (size_t)su[u] * IN_DIM + 2 * l);
            #pragma unroll
            for (int u = 0; u < 8; ++u) {
                const float4 wu = w4S[w][j0 + u];   // uniform b128 broadcast
                const float x0 = bfu(hv[u] & 0xffffu);
                const float x1 = bfu(hv[u] >> 16);
                acc[0][0] = fmaf(x0, wu.x, acc[0][0]);
                acc[0][1] = fmaf(x1, wu.x, acc[0][1]);
                acc[1][0] = fmaf(x0, wu.y, acc[1][0]);
                acc[1][1] = fmaf(x1, wu.y, acc[1][1]);
                acc[2][0] = fmaf(x0, wu.z, acc[2][0]);
                acc[2][1] = fmaf(x1, wu.z, acc[2][1]);
                acc[3][0] = fmaf(x0, wu.w, acc[3][0]);
                acc[3][1] = fmaf(x1, wu.w, acc[3][1]);
            }
        }
    }
    #pragma unroll
    for (int off = 1; off < 64; off <<= 1) {
        ws.x += __shfl_xor(ws.x, off, 64);
        ws.y += __shfl_xor(ws.y, off, 64);
        ws.z += __shfl_xor(ws.z, off, 64);
        ws.w += __shfl_xor(ws.w, off, 64);
    }
    const float i0 = 1.f / (ws.x + 1e-16f), i1 = 1.f / (ws.y + 1e-16f);
    const float i2 = 1.f / (ws.z + 1e-16f), i3 = 1.f / (ws.w + 1e-16f);
    unsigned short* out = xagg + (size_t)n * 512 + 2 * l;
    *(unsigned int*)(out)       = (unsigned int)pk(acc[0][0] * i0) |
                                  ((unsigned int)pk(acc[0][1] * i0) << 16);
    *(unsigned int*)(out + 128) = (unsigned int)pk(acc[1][0] * i1) |
                                  ((unsigned int)pk(acc[1][1] * i1) << 16);
    *(unsigned int*)(out + 256) = (unsigned int)pk(acc[2][0] * i2) |
                                  ((unsigned int)pk(acc[2][1] * i2) << 16);
    *(unsigned int*)(out + 384) = (unsigned int)pk(acc[3][0] * i3) |
                                  ((unsigned int)pk(acc[3][1] * i3) << 16);
}

// ==== Layer-1 GEMM (post-agg, MFMA): hx = elu(xagg @ W1 + b1), block-diag ===
// xagg row = [h*128 + k]. Out col h*64+nt*16+c -> W1f tile ng = h*4+nt (same
// packing as before). Two N-halves share one 33KB LDS stage buffer.
__global__ __launch_bounds__(256) void gemm1b_k(
    const unsigned short* __restrict__ xagg, const unsigned short* __restrict__ W1f,
    const float* __restrict__ b1, unsigned short* __restrict__ hxb, int N)
{
    __shared__ short lds[64 * 264];
    const int t = threadIdx.x, w = t >> 6, l = t & 63;
    const int q = l >> 4, c = l & 15;
    const int n0 = blockIdx.x * 64;
    const int arow = 16 * w + c;
    f32x4 acc[16];
    #pragma unroll
    for (int nt = 0; nt < 16; ++nt) acc[nt] = (f32x4){0.f, 0.f, 0.f, 0.f};
    #pragma unroll
    for (int half = 0; half < 2; ++half) {
        if (half) __syncthreads();           // protect LDS reuse
        for (int i = t; i < 64 * 32; i += 256) {
            const int r = i >> 5, ch = (i & 31) * 8;
            const int rn = min(n0 + r, N - 1);
            *(short8*)&lds[r * 264 + ch] =
                *(const short8*)&xagg[(size_t)rn * 512 + half * 256 + ch];
        }
        __syncthreads();
        #pragma unroll
        for (int hh = 0; hh < 2; ++hh) {
            const int h = half * 2 + hh;
            short8 afr[4];
            #pragma unroll
            for (int kc = 0; kc < 4; ++kc)
                afr[kc] = *(const short8*)&lds[arow * 264 + hh * 128 + kc * 32 + q * 8];
            #pragma unroll
            for (int nt = 0; nt < 4; ++nt) {
                #pragma unroll
                for (int kc = 0; kc < 4; ++kc) {
                    const short8 bfr = *(const short8*)(W1f +
                        ((size_t)((h * 4 + nt) * 4 + kc) * 64 + l) * 8);
                    acc[h * 4 + nt] = __builtin_amdgcn_mfma_f32_16x16x32_bf16(
                        afr[kc], bfr, acc[h * 4 + nt], 0, 0, 0);
                }
            }
        }
    }
    __syncthreads();
    #pragma unroll
    for (int nt = 0; nt < 16; ++nt)
        #pragma unroll
        for (int r = 0; r < 4; ++r) {
            const float v = elu1(acc[nt][r] + b1[nt * 16 + c]);
            lds[(16 * w + q * 4 + r) * 264 + nt * 16 + c] = (short)pk(v);
        }
    __syncthreads();
    for (int i = t; i < 64 * 32; i += 256) {
        const int r = i >> 5, ch = (i & 31) * 8;
        const int node = n0 + r;
        if (node < N)
            *(short8*)&hxb[(size_t)node * C1 + ch] =
                *(const short8*)&lds[r * 264 + ch];
    }
}

// ============ Layer-2 GEMM (MFMA): h2 = hx @ W2 (bf16) + logits =============
__global__ __launch_bounds__(256) void gemm2_k(
    const unsigned short* __restrict__ hxb, const unsigned short* __restrict__ W2f,
    const float* __restrict__ as2, const float* __restrict__ ad2,
    unsigned short* __restrict__ h2b, float* __restrict__ a_s2,
    float* __restrict__ a_d2, int N)
{
    __shared__ short lds[64 * 264];   // stage: [row][264] (K=256+pad8)
    const int t = threadIdx.x, w = t >> 6, l = t & 63;
    const int q = l >> 4, c = l & 15;
    const int n0 = blockIdx.x * 64;
    for (int i = t; i < 64 * 32; i += 256) {
        const int r = i >> 5, ch = (i & 31) * 8;
        const int rn = min(n0 + r, N - 1);
        *(short8*)&lds[r * 264 + ch] =
            *(const short8*)&hxb[(size_t)rn * C1 + ch];
    }
    __syncthreads();
    short8 afr[8];
    const int arow = 16 * w + c;
    #pragma unroll
    for (int kc = 0; kc < 8; ++kc)
        afr[kc] = *(const short8*)&lds[arow * 264 + kc * 32 + q * 8];
    f32x4 acc[4];
    #pragma unroll
    for (int nt = 0; nt < 4; ++nt) acc[nt] = (f32x4){0.f, 0.f, 0.f, 0.f};
    #pragma unroll
    for (int nt = 0; nt < 4; ++nt) {
        #pragma unroll
        for (int kc = 0; kc < 8; ++kc) {
            const short8 bfr =
                *(const short8*)(W2f + ((size_t)(nt * 8 + kc) * 64 + l) * 8);
            acc[nt] = __builtin_amdgcn_mfma_f32_16x16x32_bf16(afr[kc], bfr,
                                                              acc[nt], 0, 0, 0);
        }
    }
    // logits (single head over all 64 cols)
    {
        float vsr[4] = {0.f, 0.f, 0.f, 0.f}, vdr[4] = {0.f, 0.f, 0.f, 0.f};
        #pragma unroll
        for (int nt = 0; nt < 4; ++nt) {
            const float sa = as2[nt * 16 + c], da = ad2[nt * 16 + c];
            #pragma unroll
            for (int r = 0; r < 4; ++r) {
                vsr[r] += acc[nt][r] * sa;
                vdr[r] += acc[nt][r] * da;
            }
        }
        #pragma unroll
        for (int r = 0; r < 4; ++r) {
            #pragma unroll
            for (int off = 1; off < 16; off <<= 1) {
                vsr[r] += __shfl_xor(vsr[r], off, 64);
                vdr[r] += __shfl_xor(vdr[r], off, 64);
            }
            const int node = n0 + 16 * w + q * 4 + r;
            if (c == 0 && node < N) {
                a_s2[node] = vsr[r];
                a_d2[node] = vdr[r];
            }
        }
    }
    __syncthreads();
    #pragma unroll
    for (int nt = 0; nt < 4; ++nt)
        #pragma unroll
        for (int r = 0; r < 4; ++r)
            lds[(16 * w + q * 4 + r) * 72 + nt * 16 + c] = (short)pk(acc[nt][r]);
    __syncthreads();
    for (int i = t; i < 64 * 8; i += 256) {
        const int r = i >> 3, ch = (i & 7) * 8;
        const int node = n0 + r;
        if (node < N)
            *(short8*)&h2b[(size_t)node * OUT_DIM + ch] =
                *(const short8*)&lds[r * 72 + ch];
    }
}

// ====== Layer-2 aggregate: 1 wave/node, lane = 2 ch; LDS-staged weights =====
// Lanes 0..31 process even edges, 32..63 odd edges of each pair. Staged
// {scol, w} pairs read back via ds_read_b64 (2 distinct addrs -> free).
__global__ __launch_bounds__(256) void agg2_k(
    const int* __restrict__ rowptr, const int* __restrict__ col,
    const float* __restrict__ a_s2, const float* __restrict__ a_d2,
    const unsigned short* __restrict__ h2b, const float* __restrict__ b2,
    float* __restrict__ zout, int N)
{
    __shared__ int2 swS[4][64];
    const int t = threadIdx.x, w = t >> 6, l = t & 63;
    const int n = blockIdx.x * 4 + w;
    if (n >= N) return;
    const int beg = rowptr[n], end = rowptr[n + 1];
    const float dn = a_d2[n];
    const int half = l >> 5, c2 = l & 31;     // lane owns ch 2*c2, 2*c2+1
    float a0 = 0.f, a1 = 0.f, wsum = 0.f;
    for (int t0 = beg; t0 < end; t0 += 64) {
        const int m = min(64, end - t0);
        const int p = t0 + l;
        int sc = 0; float wv = 0.f;
        if (p < end) {
            sc = col[p];
            wv = expc(lrelu(a_s2[sc] + dn));
            wsum += wv;
        }
        swS[w][l] = make_int2(sc, __float_as_int(wv));
        __threadfence_block();           // within-wave LDS write->read order
        const int pairs = (m + 1) >> 1;
        for (int j0 = 0; j0 < pairs; j0 += 8) {
            int2 sv[8];
            #pragma unroll
            for (int u = 0; u < 8; ++u)
                sv[u] = swS[w][2 * (j0 + u) + half];
            unsigned int hv[8];
            #pragma unroll
            for (int u = 0; u < 8; ++u)
                hv[u] = *(const unsigned int*)(h2b + (size_t)sv[u].x * OUT_DIM + 2 * c2);
            #pragma unroll
            for (int u = 0; u < 8; ++u) {
                const float wu = __int_as_float(sv[u].y);
                a0 = fmaf(bfu(hv[u] & 0xffffu), wu, a0);
                a1 = fmaf(bfu(hv[u] >> 16), wu, a1);
            }
        }
    }
    a0 += __shfl_xor(a0, 32, 64);
    a1 += __shfl_xor(a1, 32, 64);
    #pragma unroll
    for (int off = 1; off < 64; off <<= 1) wsum += __shfl_xor(wsum, off, 64);
    const float inv = 1.f / (wsum + 1e-16f);
    float z0 = a0 * inv + b2[2 * c2];
    float z1 = a1 * inv + b2[2 * c2 + 1];
    float sq = z0 * z0 + z1 * z1;
    #pragma unroll
    for (int off = 1; off < 32; off <<= 1) sq += __shfl_xor(sq, off, 64);
    const float rn = 1.f / fmaxf(sqrtf(sq), 1e-12f);
    if (l < 32) {
        float2 o; o.x = z0 * rn; o.y = z1 * rn;
        *(float2*)&zout[(size_t)n * OUT_DIM + 2 * c2] = o;
    }
}

// ================= Decoder: x_hat = elu(z@dW1+db1)@dW2+db2 =================
__global__ __launch_bounds__(256) void dec_k(
    const float* __restrict__ z,
    const float* __restrict__ dW1, const float* __restrict__ db1,
    const float* __restrict__ dW2, const float* __restrict__ db2,
    float* __restrict__ xhat, int N)
{
    __shared__ float zs[32 * 64];
    __shared__ float ts[32 * 64];
    const int t = threadIdx.x;
    const int n0 = blockIdx.x * 32;
    for (int i = t; i < 32 * 64; i += 256) {
        const int nb_l = i >> 6, k = i & 63;
        const int n = min(n0 + nb_l, N - 1);
        zs[(nb_l >> 3) * 512 + k * 8 + (nb_l & 7)] = z[(size_t)n * OUT_DIM + k];
    }
    __syncthreads();
    const int w = t >> 6, l = t & 63;
    const float* zw = zs + w * 512;
    float* tw = ts + w * 512;
    float acc[8] = {0.f, 0.f, 0.f, 0.f, 0.f, 0.f, 0.f, 0.f};
    #pragma unroll 4
    for (int k = 0; k < 64; ++k) {
        const float wv = dW1[k * HID + l];
        const float4 xa = *(const float4*)&zw[k * 8];
        const float4 xb = *(const float4*)&zw[k * 8 + 4];
        acc[0] += xa.x * wv; acc[1] += xa.y * wv;
        acc[2] += xa.z * wv; acc[3] += xa.w * wv;
        acc[4] += xb.x * wv; acc[5] += xb.y * wv;
        acc[6] += xb.z * wv; acc[7] += xb.w * wv;
    }
    const float bb = db1[l];
    #pragma unroll
    for (int nb = 0; nb < 8; ++nb) tw[l * 8 + nb] = elu1(acc[nb] + bb);
    __syncthreads();
    float a0[8] = {0.f, 0.f, 0.f, 0.f, 0.f, 0.f, 0.f, 0.f};
    float a1[8] = {0.f, 0.f, 0.f, 0.f, 0.f, 0.f, 0.f, 0.f};
    #pragma unroll 2
    for (int k = 0; k < 64; ++k) {
        const float w0 = dW2[k * IN_DIM + l];
        const float w1 = dW2[k * IN_DIM + 64 + l];
        const float4 xa = *(const float4*)&tw[k * 8];
        const float4 xb = *(const float4*)&tw[k * 8 + 4];
        const float xv[8] = {xa.x, xa.y, xa.z, xa.w, xb.x, xb.y, xb.z, xb.w};
        #pragma unroll
        for (int nb = 0; nb < 8; ++nb) {
            a0[nb] += xv[nb] * w0;
            a1[nb] += xv[nb] * w1;
        }
    }
    const float bb0 = db2[l], bb1 = db2[64 + l];
    #pragma unroll
    for (int nb = 0; nb < 8; ++nb) {
        const int n = n0 + w * 8 + nb;
        if (n >= N) break;
        xhat[(size_t)n * IN_DIM + l]      = a0[nb] + bb0;
        xhat[(size_t)n * IN_DIM + 64 + l] = a1[nb] + bb1;
    }
}

extern "C" void kernel_launch(void* const* d_in, const int* in_sizes, int n_in,
                              void* d_out, int out_size, void* d_ws, size_t ws_size,
                              hipStream_t stream)
{
    const float* x   = (const float*)d_in[0];
    const int*   ei  = (const int*)d_in[1];
    const float* W1  = (const float*)d_in[2];
    const float* as1 = (const float*)d_in[3];
    const float* ad1 = (const float*)d_in[4];
    const float* b1  = (const float*)d_in[5];
    const float* W2  = (const float*)d_in[6];
    const float* as2 = (const float*)d_in[7];
    const float* ad2 = (const float*)d_in[8];
    const float* b2  = (const float*)d_in[9];
    const float* dW1 = (const float*)d_in[10];
    const float* db1 = (const float*)d_in[11];
    const float* dW2 = (const float*)d_in[12];
    const float* db2 = (const float*)d_in[13];

    const int N    = in_sizes[0] / IN_DIM;
    const int E    = in_sizes[1] / 2;
    const int Etot = E + N;

    // fixed-size region first (keeps every u16 array 16B-aligned for any N)
    unsigned short* W1f = (unsigned short*)d_ws;           // 32768 u16
    unsigned short* W2f = W1f + 32768;                     // 16384 u16
    float* u_s = (float*)(W2f + 16384);                    // 512 f32
    float* u_d = u_s + 512;                                // 512 f32
    unsigned short* hxb  = (unsigned short*)(u_d + 512);   // N*256 u16
    unsigned short* xagg = hxb  + (size_t)N * C1;          // N*512 u16
    unsigned short* xb   = xagg + (size_t)N * 512;         // N*128 u16
    unsigned short* h2b  = xb   + (size_t)N * IN_DIM;      // N*64  u16
    float* a_s1 = (float*)(h2b + (size_t)N * OUT_DIM);     // N*4
    float* a_d1 = a_s1 + (size_t)N * HEADS;                // N*4
    float* a_s2 = a_d1 + (size_t)N * HEADS;                // N
    float* a_d2 = a_s2 + (size_t)N;                        // N
    int* rowptr = (int*)(a_d2 + (size_t)N);                // N+1
    int* cursor = rowptr + (N + 1);                        // N
    int* col    = cursor + N;                              // Etot
    int* psum   = col + Etot;                              // 256

    const size_t needed = (size_t)N * 1968 + (size_t)Etot * 4 + 103428;
    if (ws_size < needed) return;  // loud failure signature

    hipMemsetAsync(rowptr, 0, (size_t)(N + 1) * sizeof(int), stream);

    const int eblk  = (Etot + 255) / 256;
    const int SC    = (N + 255) / 256;           // <=256 chunks (N=50k -> 196)
    const int mblk  = (N + 63) / 64;
    const int nblk4 = (N + 3) / 4;
    w1f_k   <<<17, 256, 0, stream>>>(W1, as1, ad1, W1f, u_s, u_d);
    w2f_k   <<<8, 256, 0, stream>>>(W2, W2f);
    xprep_k <<<nblk4, 256, 0, stream>>>(x, u_s, u_d, xb, a_s1, a_d1, N);
    deg_k   <<<eblk, 256, 0, stream>>>(ei, E, Etot, rowptr);
    scanA_k <<<SC, 256, 0, stream>>>(rowptr, psum, N);
    scanB_k <<<1, 256, 0, stream>>>(psum, SC);
    scanC_k <<<SC, 256, 0, stream>>>(rowptr, cursor, psum, N);
    fill_k  <<<eblk, 256, 0, stream>>>(ei, E, Etot, cursor, col);
    agg1x_k <<<nblk4, 256, 0, stream>>>(rowptr, col, a_s1, a_d1, xb, xagg, N);
    gemm1b_k<<<mblk, 256, 0, stream>>>(xagg, W1f, b1, hxb, N);
    gemm2_k <<<mblk, 256, 0, stream>>>(hxb, W2f, as2, ad2, h2b, a_s2, a_d2, N);
    agg2_k  <<<nblk4, 256, 0, stream>>>(rowptr, col, a_s2, a_d2, h2b, b2,
                                        (float*)d_out, N);
    dec_k   <<<(N + 31) / 32, 256, 0, stream>>>((const float*)d_out, dW1, db1,
                                                dW2, db2,
                                                (float*)d_out + (size_t)N * OUT_DIM, N);
}

// Round 3
// 362.285 us; speedup vs baseline: 1.0803x; 1.0371x over previous
//
#include <hip/hip_runtime.h>
#include <hip/hip_bf16.h>

// GAT-GAE forward: 2x GATConv + normalize + MLP decoder. fp32 I/O, int32 edges.
// Round 12: CSR build de-amplified. fill_k's 4B random scatters caused 16x
// write amplification (55MB HBM write for a 3.4MB col[]): every store dirtied
// a lone 64B line spread across 8 non-coherent XCD L2s. Now deg/fill run as
// 8-binned kernels: bin = blockIdx&7 (~XCD via round-robin dispatch), each
// bin owns a contiguous dst-node range, so col writes densely fill a ~425KB
// L2-resident region (full-line writebacks, ~3.4MB total) and cursor/rowptr
// atomics are XCD-local. dst array re-read 8x from L3 (ei is L3-resident).
//
// Workspace (bytes): W1f 64K | W2f 32K | u_s 2K | u_d 2K |
//   hxb u16[N*256] | xagg u16[N*512] | xb u16[N*128] | h2b u16[N*64] |
//   a_s1 f32[4N] | a_d1 f32[4N] | a_s2 f32[N] | a_d2 f32[N] |
//   rowptr int[N+1] | cursor int[N] | col int[Etot] | psum int[256]

#define IN_DIM   128
#define C1       256   // HEADS*HID
#define HEADS    4
#define HID      64
#define OUT_DIM  64

typedef __attribute__((ext_vector_type(8))) short short8;
typedef __attribute__((ext_vector_type(4))) float f32x4;

__device__ __forceinline__ float lrelu(float x) { return x > 0.f ? x : 0.2f * x; }
__device__ __forceinline__ float elu1(float x)  { return x > 0.f ? x : (__expf(x) - 1.f); }
__device__ __forceinline__ float expc(float x)  { return __expf(fminf(x, 60.f)); }
__device__ __forceinline__ float bfu(unsigned int u) {
    union { unsigned int i; float f; } c; c.i = u << 16; return c.f;
}
__device__ __forceinline__ unsigned short pk(float f) {
    union { float f; unsigned int i; } c; c.f = f;
    return (unsigned short)((c.i + 0x7fffu + ((c.i >> 16) & 1u)) >> 16);
}

// ============ weight prepack: B-fragment order for 16x16x32 bf16 ============
// Blocks 0..15: W1 [128][256] fp32 -> W1f[((nt*4+kc)*64 + lane)*8 + j] =
//   bf16(W1[(kc*32 + (lane>>4)*8 + j)*256 + nt*16 + (lane&15)])
// Block 16: u_s[h*128+k] = sum_c W1[k][h*64+c]*att_src1[h][c]; u_d likewise.
__global__ __launch_bounds__(256) void w1f_k(const float* __restrict__ W1,
                                             const float* __restrict__ as1,
                                             const float* __restrict__ ad1,
                                             unsigned short* __restrict__ W1f,
                                             float* __restrict__ u_s,
                                             float* __restrict__ u_d)
{
    if (blockIdx.x == 16) {
        for (int idx = threadIdx.x; idx < 512; idx += 256) {
            const int h = idx >> 7, k = idx & 127;
            float ss = 0.f, dd = 0.f;
            #pragma unroll 4
            for (int c = 0; c < 64; ++c) {
                const float wv = W1[k * 256 + h * 64 + c];
                ss += wv * as1[h * 64 + c];
                dd += wv * ad1[h * 64 + c];
            }
            u_s[idx] = ss;
            u_d[idx] = dd;
        }
        return;
    }
    const int idx = blockIdx.x * 256 + threadIdx.x;   // 4096 lane-entries
    if (idx >= 64 * 64) return;
    const int lane = idx & 63, e = idx >> 6;
    const int nt = e >> 2, kc = e & 3, q = lane >> 4, c = lane & 15;
    unsigned short tmp[8];
    #pragma unroll
    for (int j = 0; j < 8; ++j)
        tmp[j] = pk(W1[(kc * 32 + q * 8 + j) * 256 + nt * 16 + c]);
    ushort4* dst = (ushort4*)(W1f + (size_t)idx * 8);
    dst[0] = make_ushort4(tmp[0], tmp[1], tmp[2], tmp[3]);
    dst[1] = make_ushort4(tmp[4], tmp[5], tmp[6], tmp[7]);
}

// W2 [256][64] fp32 -> W2f[((nt*8+kc)*64 + lane)*8 + j]
__global__ __launch_bounds__(256) void w2f_k(const float* __restrict__ W2,
                                             unsigned short* __restrict__ W2f)
{
    const int idx = blockIdx.x * 256 + threadIdx.x;   // 2048 lane-entries
    if (idx >= 32 * 64) return;
    const int lane = idx & 63, e = idx >> 6;
    const int nt = e >> 3, kc = e & 7, q = lane >> 4, c = lane & 15;
    unsigned short tmp[8];
    #pragma unroll
    for (int j = 0; j < 8; ++j)
        tmp[j] = pk(W2[(kc * 32 + q * 8 + j) * 64 + nt * 16 + c]);
    ushort4* dst = (ushort4*)(W2f + (size_t)idx * 8);
    dst[0] = make_ushort4(tmp[0], tmp[1], tmp[2], tmp[3]);
    dst[1] = make_ushort4(tmp[4], tmp[5], tmp[6], tmp[7]);
}

// ============ xprep: cast x->bf16 + layer-1 logits via u-vectors ============
// 1 wave/node: lane l owns channels 2l,2l+1. a_s1[n,h] = x[n]·u_s[h].
__global__ __launch_bounds__(256) void xprep_k(
    const float* __restrict__ x, const float* __restrict__ u_s,
    const float* __restrict__ u_d, unsigned short* __restrict__ xb,
    float* __restrict__ a_s1, float* __restrict__ a_d1, int N)
{
    __shared__ float us[512], ud[512];
    const int t = threadIdx.x;
    for (int i = t; i < 512; i += 256) { us[i] = u_s[i]; ud[i] = u_d[i]; }
    __syncthreads();
    const int w = t >> 6, l = t & 63;
    const int n = blockIdx.x * 4 + w;
    if (n >= N) return;
    const float2 xv = *(const float2*)&x[(size_t)n * IN_DIM + 2 * l];
    const unsigned int p2 =
        (unsigned int)pk(xv.x) | ((unsigned int)pk(xv.y) << 16);
    *(unsigned int*)&xb[(size_t)n * IN_DIM + 2 * l] = p2;
    #pragma unroll
    for (int h = 0; h < 4; ++h) {
        float ps = xv.x * us[h * 128 + 2 * l] + xv.y * us[h * 128 + 2 * l + 1];
        float pd = xv.x * ud[h * 128 + 2 * l] + xv.y * ud[h * 128 + 2 * l + 1];
        #pragma unroll
        for (int off = 1; off < 64; off <<= 1) {
            ps += __shfl_xor(ps, off, 64);
            pd += __shfl_xor(pd, off, 64);
        }
        if (l == 0) {
            a_s1[n * 4 + h] = ps;
            a_d1[n * 4 + h] = pd;
        }
    }
}

// ================= CSR build (8-binned: bin = blockIdx&7 ~ XCD) =============
__global__ __launch_bounds__(256) void deg_k(const int* __restrict__ ei, int E,
                                             int Etot, int* __restrict__ rowptr,
                                             int N)
{
    const int bin = blockIdx.x & 7;
    const int chunk = blockIdx.x >> 3, nchunk = gridDim.x >> 3;
    const int per = (Etot + nchunk - 1) / nchunk;
    const int e0 = chunk * per, e1 = min(e0 + per, Etot);
    const int lo = (int)(((long long)N * bin) >> 3);
    const int hi = (int)(((long long)N * (bin + 1)) >> 3);
    for (int e = e0 + threadIdx.x; e < e1; e += 256) {
        const int d = (e < E) ? ei[E + e] : e - E;
        if (d >= lo && d < hi) atomicAdd(&rowptr[1 + d], 1);
    }
}

__device__ __forceinline__ int blk_incl_scan(int v, int t) {
    __shared__ int wsum[4];
    const int lane = t & 63, wid = t >> 6;
    int s = v;
    #pragma unroll
    for (int off = 1; off < 64; off <<= 1) {
        const int u = __shfl_up(s, off, 64);
        if (lane >= off) s += u;
    }
    if (lane == 63) wsum[wid] = s;
    __syncthreads();
    int add = 0;
    #pragma unroll
    for (int k = 0; k < 4; ++k) if (k < wid) add += wsum[k];
    __syncthreads();
    return s + add;
}

__global__ __launch_bounds__(256) void scanA_k(const int* __restrict__ rowptr,
                                               int* __restrict__ psum, int N)
{
    const int t = threadIdx.x;
    const int i = blockIdx.x * 256 + t;
    int v = (i < N) ? rowptr[1 + i] : 0;
    #pragma unroll
    for (int off = 1; off < 64; off <<= 1) v += __shfl_xor(v, off, 64);
    __shared__ int ws[4];
    if ((t & 63) == 0) ws[t >> 6] = v;
    __syncthreads();
    if (t == 0) psum[blockIdx.x] = ws[0] + ws[1] + ws[2] + ws[3];
}

__global__ __launch_bounds__(256) void scanB_k(int* __restrict__ psum, int SC)
{
    const int t = threadIdx.x;
    const int v = (t < SC) ? psum[t] : 0;
    const int inc = blk_incl_scan(v, t);
    if (t < SC) psum[t] = inc - v;   // exclusive
}

__global__ __launch_bounds__(256) void scanC_k(int* __restrict__ rowptr,
                                               int* __restrict__ cursor,
                                               const int* __restrict__ psum, int N)
{
    const int t = threadIdx.x;
    const int i = blockIdx.x * 256 + t;
    const int v = (i < N) ? rowptr[1 + i] : 0;
    const int inc = blk_incl_scan(v, t);
    const int base = psum[blockIdx.x];
    if (i < N) {
        rowptr[1 + i] = base + inc;
        cursor[i]     = base + inc - v;
    }
}

// Binned fill: bin's col region [rowptr[lo],rowptr[hi]) (~Etot/8*4B) stays in
// the local XCD L2 and accumulates FULL dirty lines before writeback -> HBM
// write ~= col size (3.4MB) instead of 64B/edge (55MB). Bin mismatch with the
// real XCD only costs speed, never correctness (device-scope atomics).
__global__ __launch_bounds__(256) void fill_k(const int* __restrict__ ei, int E,
                                              int Etot, int* __restrict__ cursor,
                                              int* __restrict__ col, int N)
{
    const int bin = blockIdx.x & 7;
    const int chunk = blockIdx.x >> 3, nchunk = gridDim.x >> 3;
    const int per = (Etot + nchunk - 1) / nchunk;
    const int e0 = chunk * per, e1 = min(e0 + per, Etot);
    const int lo = (int)(((long long)N * bin) >> 3);
    const int hi = (int)(((long long)N * (bin + 1)) >> 3);
    for (int e = e0 + threadIdx.x; e < e1; e += 256) {
        const int d = (e < E) ? ei[E + e] : e - E;
        if (d >= lo && d < hi) {
            const int s = (e < E) ? ei[e] : d;
            const int pos = atomicAdd(&cursor[d], 1);
            col[pos] = s;
        }
    }
}

// ====== Layer-1 aggregate over x: xagg[n,h,:] = (sum_e w_e^h x[src]) / sum w ==
// 1 wave/node; lane l owns channels (2l,2l+1) for all 4 heads.
// Per 64-edge chunk: lane l stages edge (t0+l)'s {scol, float4 weights} into
// per-wave LDS; consume loop reads them via uniform ds_read (broadcast) so
// the 8-deep gather batch has no shfl chain in front of its addresses.
__global__ __launch_bounds__(256) void agg1x_k(
    const int* __restrict__ rowptr, const int* __restrict__ col,
    const float* __restrict__ a_s1, const float* __restrict__ a_d1,
    const unsigned short* __restrict__ xb, unsigned short* __restrict__ xagg,
    int N)
{
    __shared__ int    scolS[4][64];
    __shared__ float4 w4S[4][64];
    const int t = threadIdx.x, w = t >> 6, l = t & 63;
    const int n = blockIdx.x * 4 + w;
    if (n >= N) return;
    const int beg = rowptr[n], end = rowptr[n + 1];
    const float4 dv = *(const float4*)&a_d1[n * 4];
    float4 ws = {0.f, 0.f, 0.f, 0.f};
    float acc[4][2] = {{0.f,0.f},{0.f,0.f},{0.f,0.f},{0.f,0.f}};
    for (int t0 = beg; t0 < end; t0 += 64) {
        const int m = min(64, end - t0);
        const int p = t0 + l;
        int sc = 0;
        float4 wv = {0.f, 0.f, 0.f, 0.f};
        if (p < end) {
            sc = col[p];
            const float4 av = *(const float4*)&a_s1[sc * 4];
            wv.x = expc(lrelu(av.x + dv.x));
            wv.y = expc(lrelu(av.y + dv.y));
            wv.z = expc(lrelu(av.z + dv.z));
            wv.w = expc(lrelu(av.w + dv.w));
            ws.x += wv.x; ws.y += wv.y; ws.z += wv.z; ws.w += wv.w;
        }
        scolS[w][l] = sc;
        w4S[w][l]   = wv;
        __threadfence_block();           // within-wave LDS write->read order
        for (int j0 = 0; j0 < m; j0 += 8) {
            const int4 s0 = *(const int4*)&scolS[w][j0];
            const int4 s1 = *(const int4*)&scolS[w][j0 + 4];
            const int su[8] = {s0.x, s0.y, s0.z, s0.w, s1.x, s1.y, s1.z, s1.w};
            unsigned int hv[8];
            #pragma unroll
            for (int u = 0; u < 8; ++u)   // 8 gathers in flight
                hv[u] = *(const unsigned int*)(xb + (size_t)su[u] * IN_DIM + 2 * l);
            #pragma unroll
            for (int u = 0; u < 8; ++u) {
                const float4 wu = w4S[w][j0 + u];   // uniform b128 broadcast
                const float x0 = bfu(hv[u] & 0xffffu);
                const float x1 = bfu(hv[u] >> 16);
                acc[0][0] = fmaf(x0, wu.x, acc[0][0]);
                acc[0][1] = fmaf(x1, wu.x, acc[0][1]);
                acc[1][0] = fmaf(x0, wu.y, acc[1][0]);
                acc[1][1] = fmaf(x1, wu.y, acc[1][1]);
                acc[2][0] = fmaf(x0, wu.z, acc[2][0]);
                acc[2][1] = fmaf(x1, wu.z, acc[2][1]);
                acc[3][0] = fmaf(x0, wu.w, acc[3][0]);
                acc[3][1] = fmaf(x1, wu.w, acc[3][1]);
            }
        }
    }
    #pragma unroll
    for (int off = 1; off < 64; off <<= 1) {
        ws.x += __shfl_xor(ws.x, off, 64);
        ws.y += __shfl_xor(ws.y, off, 64);
        ws.z += __shfl_xor(ws.z, off, 64);
        ws.w += __shfl_xor(ws.w, off, 64);
    }
    const float i0 = 1.f / (ws.x + 1e-16f), i1 = 1.f / (ws.y + 1e-16f);
    const float i2 = 1.f / (ws.z + 1e-16f), i3 = 1.f / (ws.w + 1e-16f);
    unsigned short* out = xagg + (size_t)n * 512 + 2 * l;
    *(unsigned int*)(out)       = (unsigned int)pk(acc[0][0] * i0) |
                                  ((unsigned int)pk(acc[0][1] * i0) << 16);
    *(unsigned int*)(out + 128) = (unsigned int)pk(acc[1][0] * i1) |
                                  ((unsigned int)pk(acc[1][1] * i1) << 16);
    *(unsigned int*)(out + 256) = (unsigned int)pk(acc[2][0] * i2) |
                                  ((unsigned int)pk(acc[2][1] * i2) << 16);
    *(unsigned int*)(out + 384) = (unsigned int)pk(acc[3][0] * i3) |
                                  ((unsigned int)pk(acc[3][1] * i3) << 16);
}

// ==== Layer-1 GEMM (post-agg, MFMA): hx = elu(xagg @ W1 + b1), block-diag ===
// xagg row = [h*128 + k]. Out col h*64+nt*16+c -> W1f tile ng = h*4+nt (same
// packing as before). Two N-halves share one 33KB LDS stage buffer.
__global__ __launch_bounds__(256) void gemm1b_k(
    const unsigned short* __restrict__ xagg, const unsigned short* __restrict__ W1f,
    const float* __restrict__ b1, unsigned short* __restrict__ hxb, int N)
{
    __shared__ short lds[64 * 264];
    const int t = threadIdx.x, w = t >> 6, l = t & 63;
    const int q = l >> 4, c = l & 15;
    const int n0 = blockIdx.x * 64;
    const int arow = 16 * w + c;
    f32x4 acc[16];
    #pragma unroll
    for (int nt = 0; nt < 16; ++nt) acc[nt] = (f32x4){0.f, 0.f, 0.f, 0.f};
    #pragma unroll
    for (int half = 0; half < 2; ++half) {
        if (half) __syncthreads();           // protect LDS reuse
        for (int i = t; i < 64 * 32; i += 256) {
            const int r = i >> 5, ch = (i & 31) * 8;
            const int rn = min(n0 + r, N - 1);
            *(short8*)&lds[r * 264 + ch] =
                *(const short8*)&xagg[(size_t)rn * 512 + half * 256 + ch];
        }
        __syncthreads();
        #pragma unroll
        for (int hh = 0; hh < 2; ++hh) {
            const int h = half * 2 + hh;
            short8 afr[4];
            #pragma unroll
            for (int kc = 0; kc < 4; ++kc)
                afr[kc] = *(const short8*)&lds[arow * 264 + hh * 128 + kc * 32 + q * 8];
            #pragma unroll
            for (int nt = 0; nt < 4; ++nt) {
                #pragma unroll
                for (int kc = 0; kc < 4; ++kc) {
                    const short8 bfr = *(const short8*)(W1f +
                        ((size_t)((h * 4 + nt) * 4 + kc) * 64 + l) * 8);
                    acc[h * 4 + nt] = __builtin_amdgcn_mfma_f32_16x16x32_bf16(
                        afr[kc], bfr, acc[h * 4 + nt], 0, 0, 0);
                }
            }
        }
    }
    __syncthreads();
    #pragma unroll
    for (int nt = 0; nt < 16; ++nt)
        #pragma unroll
        for (int r = 0; r < 4; ++r) {
            const float v = elu1(acc[nt][r] + b1[nt * 16 + c]);
            lds[(16 * w + q * 4 + r) * 264 + nt * 16 + c] = (short)pk(v);
        }
    __syncthreads();
    for (int i = t; i < 64 * 32; i += 256) {
        const int r = i >> 5, ch = (i & 31) * 8;
        const int node = n0 + r;
        if (node < N)
            *(short8*)&hxb[(size_t)node * C1 + ch] =
                *(const short8*)&lds[r * 264 + ch];
    }
}

// ============ Layer-2 GEMM (MFMA): h2 = hx @ W2 (bf16) + logits =============
__global__ __launch_bounds__(256) void gemm2_k(
    const unsigned short* __restrict__ hxb, const unsigned short* __restrict__ W2f,
    const float* __restrict__ as2, const float* __restrict__ ad2,
    unsigned short* __restrict__ h2b, float* __restrict__ a_s2,
    float* __restrict__ a_d2, int N)
{
    __shared__ short lds[64 * 264];   // stage: [row][264] (K=256+pad8)
    const int t = threadIdx.x, w = t >> 6, l = t & 63;
    const int q = l >> 4, c = l & 15;
    const int n0 = blockIdx.x * 64;
    for (int i = t; i < 64 * 32; i += 256) {
        const int r = i >> 5, ch = (i & 31) * 8;
        const int rn = min(n0 + r, N - 1);
        *(short8*)&lds[r * 264 + ch] =
            *(const short8*)&hxb[(size_t)rn * C1 + ch];
    }
    __syncthreads();
    short8 afr[8];
    const int arow = 16 * w + c;
    #pragma unroll
    for (int kc = 0; kc < 8; ++kc)
        afr[kc] = *(const short8*)&lds[arow * 264 + kc * 32 + q * 8];
    f32x4 acc[4];
    #pragma unroll
    for (int nt = 0; nt < 4; ++nt) acc[nt] = (f32x4){0.f, 0.f, 0.f, 0.f};
    #pragma unroll
    for (int nt = 0; nt < 4; ++nt) {
        #pragma unroll
        for (int kc = 0; kc < 8; ++kc) {
            const short8 bfr =
                *(const short8*)(W2f + ((size_t)(nt * 8 + kc) * 64 + l) * 8);
            acc[nt] = __builtin_amdgcn_mfma_f32_16x16x32_bf16(afr[kc], bfr,
                                                              acc[nt], 0, 0, 0);
        }
    }
    // logits (single head over all 64 cols)
    {
        float vsr[4] = {0.f, 0.f, 0.f, 0.f}, vdr[4] = {0.f, 0.f, 0.f, 0.f};
        #pragma unroll
        for (int nt = 0; nt < 4; ++nt) {
            const float sa = as2[nt * 16 + c], da = ad2[nt * 16 + c];
            #pragma unroll
            for (int r = 0; r < 4; ++r) {
                vsr[r] += acc[nt][r] * sa;
                vdr[r] += acc[nt][r] * da;
            }
        }
        #pragma unroll
        for (int r = 0; r < 4; ++r) {
            #pragma unroll
            for (int off = 1; off < 16; off <<= 1) {
                vsr[r] += __shfl_xor(vsr[r], off, 64);
                vdr[r] += __shfl_xor(vdr[r], off, 64);
            }
            const int node = n0 + 16 * w + q * 4 + r;
            if (c == 0 && node < N) {
                a_s2[node] = vsr[r];
                a_d2[node] = vdr[r];
            }
        }
    }
    __syncthreads();
    #pragma unroll
    for (int nt = 0; nt < 4; ++nt)
        #pragma unroll
        for (int r = 0; r < 4; ++r)
            lds[(16 * w + q * 4 + r) * 72 + nt * 16 + c] = (short)pk(acc[nt][r]);
    __syncthreads();
    for (int i = t; i < 64 * 8; i += 256) {
        const int r = i >> 3, ch = (i & 7) * 8;
        const int node = n0 + r;
        if (node < N)
            *(short8*)&h2b[(size_t)node * OUT_DIM + ch] =
                *(const short8*)&lds[r * 72 + ch];
    }
}

// ====== Layer-2 aggregate: 1 wave/node, lane = 2 ch; LDS-staged weights =====
__global__ __launch_bounds__(256) void agg2_k(
    const int* __restrict__ rowptr, const int* __restrict__ col,
    const float* __restrict__ a_s2, const float* __restrict__ a_d2,
    const unsigned short* __restrict__ h2b, const float* __restrict__ b2,
    float* __restrict__ zout, int N)
{
    __shared__ int2 swS[4][64];
    const int t = threadIdx.x, w = t >> 6, l = t & 63;
    const int n = blockIdx.x * 4 + w;
    if (n >= N) return;
    const int beg = rowptr[n], end = rowptr[n + 1];
    const float dn = a_d2[n];
    const int half = l >> 5, c2 = l & 31;     // lane owns ch 2*c2, 2*c2+1
    float a0 = 0.f, a1 = 0.f, wsum = 0.f;
    for (int t0 = beg; t0 < end; t0 += 64) {
        const int m = min(64, end - t0);
        const int p = t0 + l;
        int sc = 0; float wv = 0.f;
        if (p < end) {
            sc = col[p];
            wv = expc(lrelu(a_s2[sc] + dn));
            wsum += wv;
        }
        swS[w][l] = make_int2(sc, __float_as_int(wv));
        __threadfence_block();           // within-wave LDS write->read order
        const int pairs = (m + 1) >> 1;
        for (int j0 = 0; j0 < pairs; j0 += 8) {
            int2 sv[8];
            #pragma unroll
            for (int u = 0; u < 8; ++u)
                sv[u] = swS[w][2 * (j0 + u) + half];
            unsigned int hv[8];
            #pragma unroll
            for (int u = 0; u < 8; ++u)
                hv[u] = *(const unsigned int*)(h2b + (size_t)sv[u].x * OUT_DIM + 2 * c2);
            #pragma unroll
            for (int u = 0; u < 8; ++u) {
                const float wu = __int_as_float(sv[u].y);
                a0 = fmaf(bfu(hv[u] & 0xffffu), wu, a0);
                a1 = fmaf(bfu(hv[u] >> 16), wu, a1);
            }
        }
    }
    a0 += __shfl_xor(a0, 32, 64);
    a1 += __shfl_xor(a1, 32, 64);
    #pragma unroll
    for (int off = 1; off < 64; off <<= 1) wsum += __shfl_xor(wsum, off, 64);
    const float inv = 1.f / (wsum + 1e-16f);
    float z0 = a0 * inv + b2[2 * c2];
    float z1 = a1 * inv + b2[2 * c2 + 1];
    float sq = z0 * z0 + z1 * z1;
    #pragma unroll
    for (int off = 1; off < 32; off <<= 1) sq += __shfl_xor(sq, off, 64);
    const float rn = 1.f / fmaxf(sqrtf(sq), 1e-12f);
    if (l < 32) {
        float2 o; o.x = z0 * rn; o.y = z1 * rn;
        *(float2*)&zout[(size_t)n * OUT_DIM + 2 * c2] = o;
    }
}

// ================= Decoder: x_hat = elu(z@dW1+db1)@dW2+db2 =================
__global__ __launch_bounds__(256) void dec_k(
    const float* __restrict__ z,
    const float* __restrict__ dW1, const float* __restrict__ db1,
    const float* __restrict__ dW2, const float* __restrict__ db2,
    float* __restrict__ xhat, int N)
{
    __shared__ float zs[32 * 64];
    __shared__ float ts[32 * 64];
    const int t = threadIdx.x;
    const int n0 = blockIdx.x * 32;
    for (int i = t; i < 32 * 64; i += 256) {
        const int nb_l = i >> 6, k = i & 63;
        const int n = min(n0 + nb_l, N - 1);
        zs[(nb_l >> 3) * 512 + k * 8 + (nb_l & 7)] = z[(size_t)n * OUT_DIM + k];
    }
    __syncthreads();
    const int w = t >> 6, l = t & 63;
    const float* zw = zs + w * 512;
    float* tw = ts + w * 512;
    float acc[8] = {0.f, 0.f, 0.f, 0.f, 0.f, 0.f, 0.f, 0.f};
    #pragma unroll 4
    for (int k = 0; k < 64; ++k) {
        const float wv = dW1[k * HID + l];
        const float4 xa = *(const float4*)&zw[k * 8];
        const float4 xb = *(const float4*)&zw[k * 8 + 4];
        acc[0] += xa.x * wv; acc[1] += xa.y * wv;
        acc[2] += xa.z * wv; acc[3] += xa.w * wv;
        acc[4] += xb.x * wv; acc[5] += xb.y * wv;
        acc[6] += xb.z * wv; acc[7] += xb.w * wv;
    }
    const float bb = db1[l];
    #pragma unroll
    for (int nb = 0; nb < 8; ++nb) tw[l * 8 + nb] = elu1(acc[nb] + bb);
    __syncthreads();
    float a0[8] = {0.f, 0.f, 0.f, 0.f, 0.f, 0.f, 0.f, 0.f};
    float a1[8] = {0.f, 0.f, 0.f, 0.f, 0.f, 0.f, 0.f, 0.f};
    #pragma unroll 2
    for (int k = 0; k < 64; ++k) {
        const float w0 = dW2[k * IN_DIM + l];
        const float w1 = dW2[k * IN_DIM + 64 + l];
        const float4 xa = *(const float4*)&tw[k * 8];
        const float4 xb = *(const float4*)&tw[k * 8 + 4];
        const float xv[8] = {xa.x, xa.y, xa.z, xa.w, xb.x, xb.y, xb.z, xb.w};
        #pragma unroll
        for (int nb = 0; nb < 8; ++nb) {
            a0[nb] += xv[nb] * w0;
            a1[nb] += xv[nb] * w1;
        }
    }
    const float bb0 = db2[l], bb1 = db2[64 + l];
    #pragma unroll
    for (int nb = 0; nb < 8; ++nb) {
        const int n = n0 + w * 8 + nb;
        if (n >= N) break;
        xhat[(size_t)n * IN_DIM + l]      = a0[nb] + bb0;
        xhat[(size_t)n * IN_DIM + 64 + l] = a1[nb] + bb1;
    }
}

extern "C" void kernel_launch(void* const* d_in, const int* in_sizes, int n_in,
                              void* d_out, int out_size, void* d_ws, size_t ws_size,
                              hipStream_t stream)
{
    const float* x   = (const float*)d_in[0];
    const int*   ei  = (const int*)d_in[1];
    const float* W1  = (const float*)d_in[2];
    const float* as1 = (const float*)d_in[3];
    const float* ad1 = (const float*)d_in[4];
    const float* b1  = (const float*)d_in[5];
    const float* W2  = (const float*)d_in[6];
    const float* as2 = (const float*)d_in[7];
    const float* ad2 = (const float*)d_in[8];
    const float* b2  = (const float*)d_in[9];
    const float* dW1 = (const float*)d_in[10];
    const float* db1 = (const float*)d_in[11];
    const float* dW2 = (const float*)d_in[12];
    const float* db2 = (const float*)d_in[13];

    const int N    = in_sizes[0] / IN_DIM;
    const int E    = in_sizes[1] / 2;
    const int Etot = E + N;

    // fixed-size region first (keeps every u16 array 16B-aligned for any N)
    unsigned short* W1f = (unsigned short*)d_ws;           // 32768 u16
    unsigned short* W2f = W1f + 32768;                     // 16384 u16
    float* u_s = (float*)(W2f + 16384);                    // 512 f32
    float* u_d = u_s + 512;                                // 512 f32
    unsigned short* hxb  = (unsigned short*)(u_d + 512);   // N*256 u16
    unsigned short* xagg = hxb  + (size_t)N * C1;          // N*512 u16
    unsigned short* xb   = xagg + (size_t)N * 512;         // N*128 u16
    unsigned short* h2b  = xb   + (size_t)N * IN_DIM;      // N*64  u16
    float* a_s1 = (float*)(h2b + (size_t)N * OUT_DIM);     // N*4
    float* a_d1 = a_s1 + (size_t)N * HEADS;                // N*4
    float* a_s2 = a_d1 + (size_t)N * HEADS;                // N
    float* a_d2 = a_s2 + (size_t)N;                        // N
    int* rowptr = (int*)(a_d2 + (size_t)N);                // N+1
    int* cursor = rowptr + (N + 1);                        // N
    int* col    = cursor + N;                              // Etot
    int* psum   = col + Etot;                              // 256

    const size_t needed = (size_t)N * 1968 + (size_t)Etot * 4 + 103428;
    if (ws_size < needed) return;  // loud failure signature

    hipMemsetAsync(rowptr, 0, (size_t)(N + 1) * sizeof(int), stream);

    const int SC    = (N + 255) / 256;           // <=256 chunks (N=50k -> 196)
    const int mblk  = (N + 63) / 64;
    const int nblk4 = (N + 3) / 4;
    const int nchunk = (Etot + 2047) / 2048;     // ~2k edges per chunk
    const int bgrid  = nchunk * 8;               // 8 bins x chunks
    w1f_k   <<<17, 256, 0, stream>>>(W1, as1, ad1, W1f, u_s, u_d);
    w2f_k   <<<8, 256, 0, stream>>>(W2, W2f);
    xprep_k <<<nblk4, 256, 0, stream>>>(x, u_s, u_d, xb, a_s1, a_d1, N);
    deg_k   <<<bgrid, 256, 0, stream>>>(ei, E, Etot, rowptr, N);
    scanA_k <<<SC, 256, 0, stream>>>(rowptr, psum, N);
    scanB_k <<<1, 256, 0, stream>>>(psum, SC);
    scanC_k <<<SC, 256, 0, stream>>>(rowptr, cursor, psum, N);
    fill_k  <<<bgrid, 256, 0, stream>>>(ei, E, Etot, cursor, col, N);
    agg1x_k <<<nblk4, 256, 0, stream>>>(rowptr, col, a_s1, a_d1, xb, xagg, N);
    gemm1b_k<<<mblk, 256, 0, stream>>>(xagg, W1f, b1, hxb, N);
    gemm2_k <<<mblk, 256, 0, stream>>>(hxb, W2f, as2, ad2, h2b, a_s2, a_d2, N);
    agg2_k  <<<nblk4, 256, 0, stream>>>(rowptr, col, a_s2, a_d2, h2b, b2,
                                        (float*)d_out, N);
    dec_k   <<<(N + 31) / 32, 256, 0, stream>>>((const float*)d_out, dW1, db1,
                                                dW2, db2,
                                                (float*)d_out + (size_t)N * OUT_DIM, N);
}

// Round 5
// 356.003 us; speedup vs baseline: 1.0994x; 1.0176x over previous
//
#include <hip/hip_runtime.h>
#include <hip/hip_bf16.h>

// GAT-GAE forward: 2x GATConv + normalize + MLP decoder. fp32 I/O, int32 edges.
// Round 14 (= R13 fixed): v_pk_fma_f32 is VOP3P -- ALL operands are 64-bit
// pairs; scalar-broadcast src1 must still be a register PAIR with op_sel
// choosing the half. agg1x reads weights as two f32x2 pairs ({w0,w1},{w2,w3})
// and uses op_sel_hi:[1,0,1] (both halves read lo) / op_sel:[0,1,0] (both
// read hi). agg2 bit-casts its staged int2{scol,w} as the pair (w = hi half).
// Per-edge VALU: agg1x 8 fma -> 4 pk_fma; agg2 2 fma -> 1 pk_fma.
//
// Workspace (bytes): W1f 64K | W2f 32K | u_s 2K | u_d 2K |
//   hxb u16[N*256] | xagg u16[N*512] | xb u16[N*128] | h2b u16[N*64] |
//   a_s1 f32[4N] | a_d1 f32[4N] | a_s2 f32[N] | a_d2 f32[N] |
//   rowptr int[N+1] | cursor int[N] | col int[Etot] | psum int[256]

#define IN_DIM   128
#define C1       256   // HEADS*HID
#define HEADS    4
#define HID      64
#define OUT_DIM  64

typedef __attribute__((ext_vector_type(8))) short short8;
typedef __attribute__((ext_vector_type(4))) float f32x4;
typedef __attribute__((ext_vector_type(2))) float f32x2;

__device__ __forceinline__ float lrelu(float x) { return x > 0.f ? x : 0.2f * x; }
__device__ __forceinline__ float elu1(float x)  { return x > 0.f ? x : (__expf(x) - 1.f); }
__device__ __forceinline__ float expc(float x)  { return __expf(fminf(x, 60.f)); }
__device__ __forceinline__ float bfu(unsigned int u) {
    union { unsigned int i; float f; } c; c.i = u << 16; return c.f;
}
__device__ __forceinline__ unsigned short pk(float f) {
    union { float f; unsigned int i; } c; c.f = f;
    return (unsigned short)((c.i + 0x7fffu + ((c.i >> 16) & 1u)) >> 16);
}
// acc.{lo,hi} += x.{lo,hi} * wpair.lo   (both result halves read src1 LO)
__device__ __forceinline__ void pkfma_lo(f32x2& acc, const f32x2 x, const f32x2 wp) {
    asm("v_pk_fma_f32 %0, %1, %2, %0 op_sel_hi:[1,0,1]"
        : "+v"(acc) : "v"(x), "v"(wp));
}
// acc.{lo,hi} += x.{lo,hi} * wpair.hi   (both result halves read src1 HI)
__device__ __forceinline__ void pkfma_hi(f32x2& acc, const f32x2 x, const f32x2 wp) {
    asm("v_pk_fma_f32 %0, %1, %2, %0 op_sel:[0,1,0] op_sel_hi:[1,1,1]"
        : "+v"(acc) : "v"(x), "v"(wp));
}
// unpack bf16 pair (lo,hi of u32) into packed f32x2
__device__ __forceinline__ f32x2 bf2up(unsigned int u) {
    union { unsigned int i[2]; f32x2 f; } c;
    c.i[0] = u << 16;
    c.i[1] = u & 0xffff0000u;
    return c.f;
}

// ============ weight prepack: B-fragment order for 16x16x32 bf16 ============
// Blocks 0..15: W1 [128][256] fp32 -> W1f[((nt*4+kc)*64 + lane)*8 + j] =
//   bf16(W1[(kc*32 + (lane>>4)*8 + j)*256 + nt*16 + (lane&15)])
// Block 16: u_s[h*128+k] = sum_c W1[k][h*64+c]*att_src1[h][c]; u_d likewise.
__global__ __launch_bounds__(256) void w1f_k(const float* __restrict__ W1,
                                             const float* __restrict__ as1,
                                             const float* __restrict__ ad1,
                                             unsigned short* __restrict__ W1f,
                                             float* __restrict__ u_s,
                                             float* __restrict__ u_d)
{
    if (blockIdx.x == 16) {
        for (int idx = threadIdx.x; idx < 512; idx += 256) {
            const int h = idx >> 7, k = idx & 127;
            float ss = 0.f, dd = 0.f;
            #pragma unroll 4
            for (int c = 0; c < 64; ++c) {
                const float wv = W1[k * 256 + h * 64 + c];
                ss += wv * as1[h * 64 + c];
                dd += wv * ad1[h * 64 + c];
            }
            u_s[idx] = ss;
            u_d[idx] = dd;
        }
        return;
    }
    const int idx = blockIdx.x * 256 + threadIdx.x;   // 4096 lane-entries
    if (idx >= 64 * 64) return;
    const int lane = idx & 63, e = idx >> 6;
    const int nt = e >> 2, kc = e & 3, q = lane >> 4, c = lane & 15;
    unsigned short tmp[8];
    #pragma unroll
    for (int j = 0; j < 8; ++j)
        tmp[j] = pk(W1[(kc * 32 + q * 8 + j) * 256 + nt * 16 + c]);
    ushort4* dst = (ushort4*)(W1f + (size_t)idx * 8);
    dst[0] = make_ushort4(tmp[0], tmp[1], tmp[2], tmp[3]);
    dst[1] = make_ushort4(tmp[4], tmp[5], tmp[6], tmp[7]);
}

// W2 [256][64] fp32 -> W2f[((nt*8+kc)*64 + lane)*8 + j]
__global__ __launch_bounds__(256) void w2f_k(const float* __restrict__ W2,
                                             unsigned short* __restrict__ W2f)
{
    const int idx = blockIdx.x * 256 + threadIdx.x;   // 2048 lane-entries
    if (idx >= 32 * 64) return;
    const int lane = idx & 63, e = idx >> 6;
    const int nt = e >> 3, kc = e & 7, q = lane >> 4, c = lane & 15;
    unsigned short tmp[8];
    #pragma unroll
    for (int j = 0; j < 8; ++j)
        tmp[j] = pk(W2[(kc * 32 + q * 8 + j) * 64 + nt * 16 + c]);
    ushort4* dst = (ushort4*)(W2f + (size_t)idx * 8);
    dst[0] = make_ushort4(tmp[0], tmp[1], tmp[2], tmp[3]);
    dst[1] = make_ushort4(tmp[4], tmp[5], tmp[6], tmp[7]);
}

// ============ xprep: cast x->bf16 + layer-1 logits via u-vectors ============
// 1 wave/node: lane l owns channels 2l,2l+1. a_s1[n,h] = x[n]·u_s[h].
__global__ __launch_bounds__(256) void xprep_k(
    const float* __restrict__ x, const float* __restrict__ u_s,
    const float* __restrict__ u_d, unsigned short* __restrict__ xb,
    float* __restrict__ a_s1, float* __restrict__ a_d1, int N)
{
    __shared__ float us[512], ud[512];
    const int t = threadIdx.x;
    for (int i = t; i < 512; i += 256) { us[i] = u_s[i]; ud[i] = u_d[i]; }
    __syncthreads();
    const int w = t >> 6, l = t & 63;
    const int n = blockIdx.x * 4 + w;
    if (n >= N) return;
    const float2 xv = *(const float2*)&x[(size_t)n * IN_DIM + 2 * l];
    const unsigned int p2 =
        (unsigned int)pk(xv.x) | ((unsigned int)pk(xv.y) << 16);
    *(unsigned int*)&xb[(size_t)n * IN_DIM + 2 * l] = p2;
    #pragma unroll
    for (int h = 0; h < 4; ++h) {
        float ps = xv.x * us[h * 128 + 2 * l] + xv.y * us[h * 128 + 2 * l + 1];
        float pd = xv.x * ud[h * 128 + 2 * l] + xv.y * ud[h * 128 + 2 * l + 1];
        #pragma unroll
        for (int off = 1; off < 64; off <<= 1) {
            ps += __shfl_xor(ps, off, 64);
            pd += __shfl_xor(pd, off, 64);
        }
        if (l == 0) {
            a_s1[n * 4 + h] = ps;
            a_d1[n * 4 + h] = pd;
        }
    }
}

// ================= CSR build (8-binned: bin = blockIdx&7 ~ XCD) =============
__global__ __launch_bounds__(256) void deg_k(const int* __restrict__ ei, int E,
                                             int Etot, int* __restrict__ rowptr,
                                             int N)
{
    const int bin = blockIdx.x & 7;
    const int chunk = blockIdx.x >> 3, nchunk = gridDim.x >> 3;
    const int per = (Etot + nchunk - 1) / nchunk;
    const int e0 = chunk * per, e1 = min(e0 + per, Etot);
    const int lo = (int)(((long long)N * bin) >> 3);
    const int hi = (int)(((long long)N * (bin + 1)) >> 3);
    for (int e = e0 + threadIdx.x; e < e1; e += 256) {
        const int d = (e < E) ? ei[E + e] : e - E;
        if (d >= lo && d < hi) atomicAdd(&rowptr[1 + d], 1);
    }
}

__device__ __forceinline__ int blk_incl_scan(int v, int t) {
    __shared__ int wsum[4];
    const int lane = t & 63, wid = t >> 6;
    int s = v;
    #pragma unroll
    for (int off = 1; off < 64; off <<= 1) {
        const int u = __shfl_up(s, off, 64);
        if (lane >= off) s += u;
    }
    if (lane == 63) wsum[wid] = s;
    __syncthreads();
    int add = 0;
    #pragma unroll
    for (int k = 0; k < 4; ++k) if (k < wid) add += wsum[k];
    __syncthreads();
    return s + add;
}

__global__ __launch_bounds__(256) void scanA_k(const int* __restrict__ rowptr,
                                               int* __restrict__ psum, int N)
{
    const int t = threadIdx.x;
    const int i = blockIdx.x * 256 + t;
    int v = (i < N) ? rowptr[1 + i] : 0;
    #pragma unroll
    for (int off = 1; off < 64; off <<= 1) v += __shfl_xor(v, off, 64);
    __shared__ int ws[4];
    if ((t & 63) == 0) ws[t >> 6] = v;
    __syncthreads();
    if (t == 0) psum[blockIdx.x] = ws[0] + ws[1] + ws[2] + ws[3];
}

__global__ __launch_bounds__(256) void scanB_k(int* __restrict__ psum, int SC)
{
    const int t = threadIdx.x;
    const int v = (t < SC) ? psum[t] : 0;
    const int inc = blk_incl_scan(v, t);
    if (t < SC) psum[t] = inc - v;   // exclusive
}

__global__ __launch_bounds__(256) void scanC_k(int* __restrict__ rowptr,
                                               int* __restrict__ cursor,
                                               const int* __restrict__ psum, int N)
{
    const int t = threadIdx.x;
    const int i = blockIdx.x * 256 + t;
    const int v = (i < N) ? rowptr[1 + i] : 0;
    const int inc = blk_incl_scan(v, t);
    const int base = psum[blockIdx.x];
    if (i < N) {
        rowptr[1 + i] = base + inc;
        cursor[i]     = base + inc - v;
    }
}

// Binned fill: bin's col region stays in the local XCD L2 and accumulates
// FULL dirty lines before writeback (R12: 55MB -> ~3.4MB HBM writes).
__global__ __launch_bounds__(256) void fill_k(const int* __restrict__ ei, int E,
                                              int Etot, int* __restrict__ cursor,
                                              int* __restrict__ col, int N)
{
    const int bin = blockIdx.x & 7;
    const int chunk = blockIdx.x >> 3, nchunk = gridDim.x >> 3;
    const int per = (Etot + nchunk - 1) / nchunk;
    const int e0 = chunk * per, e1 = min(e0 + per, Etot);
    const int lo = (int)(((long long)N * bin) >> 3);
    const int hi = (int)(((long long)N * (bin + 1)) >> 3);
    for (int e = e0 + threadIdx.x; e < e1; e += 256) {
        const int d = (e < E) ? ei[E + e] : e - E;
        if (d >= lo && d < hi) {
            const int s = (e < E) ? ei[e] : d;
            const int pos = atomicAdd(&cursor[d], 1);
            col[pos] = s;
        }
    }
}

// ====== Layer-1 aggregate over x: xagg[n,h,:] = (sum_e w_e^h x[src]) / sum w ==
// 1 wave/node; lane l owns channels (2l,2l+1) for all 4 heads (packed f32x2
// per head, v_pk_fma_f32 with op_sel half-select). Per 64-edge chunk: lane l
// stages edge (t0+l)'s {scol, float4 weights} into per-wave LDS; consume loop
// reads them via uniform ds_read (broadcast) -- no cross-lane chain in front
// of the 8-deep gather batch.
__global__ __launch_bounds__(256) void agg1x_k(
    const int* __restrict__ rowptr, const int* __restrict__ col,
    const float* __restrict__ a_s1, const float* __restrict__ a_d1,
    const unsigned short* __restrict__ xb, unsigned short* __restrict__ xagg,
    int N)
{
    __shared__ int    scolS[4][64];
    __shared__ float4 w4S[4][64];
    const int t = threadIdx.x, w = t >> 6, l = t & 63;
    const int n = blockIdx.x * 4 + w;
    if (n >= N) return;
    const int beg = rowptr[n], end = rowptr[n + 1];
    const float4 dv = *(const float4*)&a_d1[n * 4];
    float4 ws = {0.f, 0.f, 0.f, 0.f};
    f32x2 acc[4] = {{0.f,0.f},{0.f,0.f},{0.f,0.f},{0.f,0.f}};
    const unsigned short* xbl = xb + 2 * l;
    for (int t0 = beg; t0 < end; t0 += 64) {
        const int m = min(64, end - t0);
        const int p = t0 + l;
        int sc = 0;
        float4 wv = {0.f, 0.f, 0.f, 0.f};
        if (p < end) {
            sc = col[p];
            const float4 av = *(const float4*)&a_s1[sc * 4];
            wv.x = expc(lrelu(av.x + dv.x));
            wv.y = expc(lrelu(av.y + dv.y));
            wv.z = expc(lrelu(av.z + dv.z));
            wv.w = expc(lrelu(av.w + dv.w));
            ws.x += wv.x; ws.y += wv.y; ws.z += wv.z; ws.w += wv.w;
        }
        scolS[w][l] = sc;
        w4S[w][l]   = wv;
        __threadfence_block();           // within-wave LDS write->read order
        for (int j0 = 0; j0 < m; j0 += 8) {
            const int4 s0 = *(const int4*)&scolS[w][j0];
            const int4 s1 = *(const int4*)&scolS[w][j0 + 4];
            const int su[8] = {s0.x, s0.y, s0.z, s0.w, s1.x, s1.y, s1.z, s1.w};
            unsigned int hv[8];
            #pragma unroll
            for (int u = 0; u < 8; ++u)   // 8 gathers in flight
                hv[u] = *(const unsigned int*)(xbl + (size_t)su[u] * IN_DIM);
            #pragma unroll
            for (int u = 0; u < 8; ++u) {
                const float* wb = (const float*)&w4S[w][j0 + u];
                const f32x2 wp01 = *(const f32x2*)(wb);      // {w0,w1}
                const f32x2 wp23 = *(const f32x2*)(wb + 2);  // {w2,w3}
                const f32x2 xv = bf2up(hv[u]);
                pkfma_lo(acc[0], xv, wp01);
                pkfma_hi(acc[1], xv, wp01);
                pkfma_lo(acc[2], xv, wp23);
                pkfma_hi(acc[3], xv, wp23);
            }
        }
    }
    #pragma unroll
    for (int off = 1; off < 64; off <<= 1) {
        ws.x += __shfl_xor(ws.x, off, 64);
        ws.y += __shfl_xor(ws.y, off, 64);
        ws.z += __shfl_xor(ws.z, off, 64);
        ws.w += __shfl_xor(ws.w, off, 64);
    }
    const float i0 = 1.f / (ws.x + 1e-16f), i1 = 1.f / (ws.y + 1e-16f);
    const float i2 = 1.f / (ws.z + 1e-16f), i3 = 1.f / (ws.w + 1e-16f);
    unsigned short* out = xagg + (size_t)n * 512 + 2 * l;
    *(unsigned int*)(out)       = (unsigned int)pk(acc[0][0] * i0) |
                                  ((unsigned int)pk(acc[0][1] * i0) << 16);
    *(unsigned int*)(out + 128) = (unsigned int)pk(acc[1][0] * i1) |
                                  ((unsigned int)pk(acc[1][1] * i1) << 16);
    *(unsigned int*)(out + 256) = (unsigned int)pk(acc[2][0] * i2) |
                                  ((unsigned int)pk(acc[2][1] * i2) << 16);
    *(unsigned int*)(out + 384) = (unsigned int)pk(acc[3][0] * i3) |
                                  ((unsigned int)pk(acc[3][1] * i3) << 16);
}

// ==== Layer-1 GEMM (post-agg, MFMA): hx = elu(xagg @ W1 + b1), block-diag ===
// xagg row = [h*128 + k]. Out col h*64+nt*16+c -> W1f tile ng = h*4+nt (same
// packing as before). Two N-halves share one 33KB LDS stage buffer.
__global__ __launch_bounds__(256) void gemm1b_k(
    const unsigned short* __restrict__ xagg, const unsigned short* __restrict__ W1f,
    const float* __restrict__ b1, unsigned short* __restrict__ hxb, int N)
{
    __shared__ short lds[64 * 264];
    const int t = threadIdx.x, w = t >> 6, l = t & 63;
    const int q = l >> 4, c = l & 15;
    const int n0 = blockIdx.x * 64;
    const int arow = 16 * w + c;
    f32x4 acc[16];
    #pragma unroll
    for (int nt = 0; nt < 16; ++nt) acc[nt] = (f32x4){0.f, 0.f, 0.f, 0.f};
    #pragma unroll
    for (int half = 0; half < 2; ++half) {
        if (half) __syncthreads();           // protect LDS reuse
        for (int i = t; i < 64 * 32; i += 256) {
            const int r = i >> 5, ch = (i & 31) * 8;
            const int rn = min(n0 + r, N - 1);
            *(short8*)&lds[r * 264 + ch] =
                *(const short8*)&xagg[(size_t)rn * 512 + half * 256 + ch];
        }
        __syncthreads();
        #pragma unroll
        for (int hh = 0; hh < 2; ++hh) {
            const int h = half * 2 + hh;
            short8 afr[4];
            #pragma unroll
            for (int kc = 0; kc < 4; ++kc)
                afr[kc] = *(const short8*)&lds[arow * 264 + hh * 128 + kc * 32 + q * 8];
            #pragma unroll
            for (int nt = 0; nt < 4; ++nt) {
                #pragma unroll
                for (int kc = 0; kc < 4; ++kc) {
                    const short8 bfr = *(const short8*)(W1f +
                        ((size_t)((h * 4 + nt) * 4 + kc) * 64 + l) * 8);
                    acc[h * 4 + nt] = __builtin_amdgcn_mfma_f32_16x16x32_bf16(
                        afr[kc], bfr, acc[h * 4 + nt], 0, 0, 0);
                }
            }
        }
    }
    __syncthreads();
    #pragma unroll
    for (int nt = 0; nt < 16; ++nt)
        #pragma unroll
        for (int r = 0; r < 4; ++r) {
            const float v = elu1(acc[nt][r] + b1[nt * 16 + c]);
            lds[(16 * w + q * 4 + r) * 264 + nt * 16 + c] = (short)pk(v);
        }
    __syncthreads();
    for (int i = t; i < 64 * 32; i += 256) {
        const int r = i >> 5, ch = (i & 31) * 8;
        const int node = n0 + r;
        if (node < N)
            *(short8*)&hxb[(size_t)node * C1 + ch] =
                *(const short8*)&lds[r * 264 + ch];
    }
}

// ============ Layer-2 GEMM (MFMA): h2 = hx @ W2 (bf16) + logits =============
__global__ __launch_bounds__(256) void gemm2_k(
    const unsigned short* __restrict__ hxb, const unsigned short* __restrict__ W2f,
    const float* __restrict__ as2, const float* __restrict__ ad2,
    unsigned short* __restrict__ h2b, float* __restrict__ a_s2,
    float* __restrict__ a_d2, int N)
{
    __shared__ short lds[64 * 264];   // stage: [row][264] (K=256+pad8)
    const int t = threadIdx.x, w = t >> 6, l = t & 63;
    const int q = l >> 4, c = l & 15;
    const int n0 = blockIdx.x * 64;
    for (int i = t; i < 64 * 32; i += 256) {
        const int r = i >> 5, ch = (i & 31) * 8;
        const int rn = min(n0 + r, N - 1);
        *(short8*)&lds[r * 264 + ch] =
            *(const short8*)&hxb[(size_t)rn * C1 + ch];
    }
    __syncthreads();
    short8 afr[8];
    const int arow = 16 * w + c;
    #pragma unroll
    for (int kc = 0; kc < 8; ++kc)
        afr[kc] = *(const short8*)&lds[arow * 264 + kc * 32 + q * 8];
    f32x4 acc[4];
    #pragma unroll
    for (int nt = 0; nt < 4; ++nt) acc[nt] = (f32x4){0.f, 0.f, 0.f, 0.f};
    #pragma unroll
    for (int nt = 0; nt < 4; ++nt) {
        #pragma unroll
        for (int kc = 0; kc < 8; ++kc) {
            const short8 bfr =
                *(const short8*)(W2f + ((size_t)(nt * 8 + kc) * 64 + l) * 8);
            acc[nt] = __builtin_amdgcn_mfma_f32_16x16x32_bf16(afr[kc], bfr,
                                                              acc[nt], 0, 0, 0);
        }
    }
    // logits (single head over all 64 cols)
    {
        float vsr[4] = {0.f, 0.f, 0.f, 0.f}, vdr[4] = {0.f, 0.f, 0.f, 0.f};
        #pragma unroll
        for (int nt = 0; nt < 4; ++nt) {
            const float sa = as2[nt * 16 + c], da = ad2[nt * 16 + c];
            #pragma unroll
            for (int r = 0; r < 4; ++r) {
                vsr[r] += acc[nt][r] * sa;
                vdr[r] += acc[nt][r] * da;
            }
        }
        #pragma unroll
        for (int r = 0; r < 4; ++r) {
            #pragma unroll
            for (int off = 1; off < 16; off <<= 1) {
                vsr[r] += __shfl_xor(vsr[r], off, 64);
                vdr[r] += __shfl_xor(vdr[r], off, 64);
            }
            const int node = n0 + 16 * w + q * 4 + r;
            if (c == 0 && node < N) {
                a_s2[node] = vsr[r];
                a_d2[node] = vdr[r];
            }
        }
    }
    __syncthreads();
    #pragma unroll
    for (int nt = 0; nt < 4; ++nt)
        #pragma unroll
        for (int r = 0; r < 4; ++r)
            lds[(16 * w + q * 4 + r) * 72 + nt * 16 + c] = (short)pk(acc[nt][r]);
    __syncthreads();
    for (int i = t; i < 64 * 8; i += 256) {
        const int r = i >> 3, ch = (i & 7) * 8;
        const int node = n0 + r;
        if (node < N)
            *(short8*)&h2b[(size_t)node * OUT_DIM + ch] =
                *(const short8*)&lds[r * 72 + ch];
    }
}

// ====== Layer-2 aggregate: 1 wave/node, lane = 2 ch; LDS-staged weights =====
// Staged int2{scol,w} IS the 64-bit pair for pk_fma (w in hi half).
__global__ __launch_bounds__(256) void agg2_k(
    const int* __restrict__ rowptr, const int* __restrict__ col,
    const float* __restrict__ a_s2, const float* __restrict__ a_d2,
    const unsigned short* __restrict__ h2b, const float* __restrict__ b2,
    float* __restrict__ zout, int N)
{
    __shared__ int2 swS[4][64];
    const int t = threadIdx.x, w = t >> 6, l = t & 63;
    const int n = blockIdx.x * 4 + w;
    if (n >= N) return;
    const int beg = rowptr[n], end = rowptr[n + 1];
    const float dn = a_d2[n];
    const int half = l >> 5, c2 = l & 31;     // lane owns ch 2*c2, 2*c2+1
    f32x2 acc = {0.f, 0.f};
    float wsum = 0.f;
    const unsigned short* h2l = h2b + 2 * c2;
    for (int t0 = beg; t0 < end; t0 += 64) {
        const int m = min(64, end - t0);
        const int p = t0 + l;
        int sc = 0; float wv = 0.f;
        if (p < end) {
            sc = col[p];
            wv = expc(lrelu(a_s2[sc] + dn));
            wsum += wv;
        }
        swS[w][l] = make_int2(sc, __float_as_int(wv));
        __threadfence_block();           // within-wave LDS write->read order
        const int pairs = (m + 1) >> 1;
        for (int j0 = 0; j0 < pairs; j0 += 8) {
            int2 sv[8];
            #pragma unroll
            for (int u = 0; u < 8; ++u)
                sv[u] = swS[w][2 * (j0 + u) + half];
            unsigned int hv[8];
            #pragma unroll
            for (int u = 0; u < 8; ++u)
                hv[u] = *(const unsigned int*)(h2l + (size_t)sv[u].x * OUT_DIM);
            #pragma unroll
            for (int u = 0; u < 8; ++u) {
                union { int2 i; f32x2 f; } cv; cv.i = sv[u];
                pkfma_hi(acc, bf2up(hv[u]), cv.f);
            }
        }
    }
    float a0 = acc[0], a1 = acc[1];
    a0 += __shfl_xor(a0, 32, 64);
    a1 += __shfl_xor(a1, 32, 64);
    #pragma unroll
    for (int off = 1; off < 64; off <<= 1) wsum += __shfl_xor(wsum, off, 64);
    const float inv = 1.f / (wsum + 1e-16f);
    float z0 = a0 * inv + b2[2 * c2];
    float z1 = a1 * inv + b2[2 * c2 + 1];
    float sq = z0 * z0 + z1 * z1;
    #pragma unroll
    for (int off = 1; off < 32; off <<= 1) sq += __shfl_xor(sq, off, 64);
    const float rn = 1.f / fmaxf(sqrtf(sq), 1e-12f);
    if (l < 32) {
        float2 o; o.x = z0 * rn; o.y = z1 * rn;
        *(float2*)&zout[(size_t)n * OUT_DIM + 2 * c2] = o;
    }
}

// ================= Decoder: x_hat = elu(z@dW1+db1)@dW2+db2 =================
__global__ __launch_bounds__(256) void dec_k(
    const float* __restrict__ z,
    const float* __restrict__ dW1, const float* __restrict__ db1,
    const float* __restrict__ dW2, const float* __restrict__ db2,
    float* __restrict__ xhat, int N)
{
    __shared__ float zs[32 * 64];
    __shared__ float ts[32 * 64];
    const int t = threadIdx.x;
    const int n0 = blockIdx.x * 32;
    for (int i = t; i < 32 * 64; i += 256) {
        const int nb_l = i >> 6, k = i & 63;
        const int n = min(n0 + nb_l, N - 1);
        zs[(nb_l >> 3) * 512 + k * 8 + (nb_l & 7)] = z[(size_t)n * OUT_DIM + k];
    }
    __syncthreads();
    const int w = t >> 6, l = t & 63;
    const float* zw = zs + w * 512;
    float* tw = ts + w * 512;
    float acc[8] = {0.f, 0.f, 0.f, 0.f, 0.f, 0.f, 0.f, 0.f};
    #pragma unroll 4
    for (int k = 0; k < 64; ++k) {
        const float wv = dW1[k * HID + l];
        const float4 xa = *(const float4*)&zw[k * 8];
        const float4 xb = *(const float4*)&zw[k * 8 + 4];
        acc[0] += xa.x * wv; acc[1] += xa.y * wv;
        acc[2] += xa.z * wv; acc[3] += xa.w * wv;
        acc[4] += xb.x * wv; acc[5] += xb.y * wv;
        acc[6] += xb.z * wv; acc[7] += xb.w * wv;
    }
    const float bb = db1[l];
    #pragma unroll
    for (int nb = 0; nb < 8; ++nb) tw[l * 8 + nb] = elu1(acc[nb] + bb);
    __syncthreads();
    float a0[8] = {0.f, 0.f, 0.f, 0.f, 0.f, 0.f, 0.f, 0.f};
    float a1[8] = {0.f, 0.f, 0.f, 0.f, 0.f, 0.f, 0.f, 0.f};
    #pragma unroll 2
    for (int k = 0; k < 64; ++k) {
        const float w0 = dW2[k * IN_DIM + l];
        const float w1 = dW2[k * IN_DIM + 64 + l];
        const float4 xa = *(const float4*)&tw[k * 8];
        const float4 xb = *(const float4*)&tw[k * 8 + 4];
        const float xv[8] = {xa.x, xa.y, xa.z, xa.w, xb.x, xb.y, xb.z, xb.w};
        #pragma unroll
        for (int nb = 0; nb < 8; ++nb) {
            a0[nb] += xv[nb] * w0;
            a1[nb] += xv[nb] * w1;
        }
    }
    const float bb0 = db2[l], bb1 = db2[64 + l];
    #pragma unroll
    for (int nb = 0; nb < 8; ++nb) {
        const int n = n0 + w * 8 + nb;
        if (n >= N) break;
        xhat[(size_t)n * IN_DIM + l]      = a0[nb] + bb0;
        xhat[(size_t)n * IN_DIM + 64 + l] = a1[nb] + bb1;
    }
}

extern "C" void kernel_launch(void* const* d_in, const int* in_sizes, int n_in,
                              void* d_out, int out_size, void* d_ws, size_t ws_size,
                              hipStream_t stream)
{
    const float* x   = (const float*)d_in[0];
    const int*   ei  = (const int*)d_in[1];
    const float* W1  = (const float*)d_in[2];
    const float* as1 = (const float*)d_in[3];
    const float* ad1 = (const float*)d_in[4];
    const float* b1  = (const float*)d_in[5];
    const float* W2  = (const float*)d_in[6];
    const float* as2 = (const float*)d_in[7];
    const float* ad2 = (const float*)d_in[8];
    const float* b2  = (const float*)d_in[9];
    const float* dW1 = (const float*)d_in[10];
    const float* db1 = (const float*)d_in[11];
    const float* dW2 = (const float*)d_in[12];
    const float* db2 = (const float*)d_in[13];

    const int N    = in_sizes[0] / IN_DIM;
    const int E    = in_sizes[1] / 2;
    const int Etot = E + N;

    // fixed-size region first (keeps every u16 array 16B-aligned for any N)
    unsigned short* W1f = (unsigned short*)d_ws;           // 32768 u16
    unsigned short* W2f = W1f + 32768;                     // 16384 u16
    float* u_s = (float*)(W2f + 16384);                    // 512 f32
    float* u_d = u_s + 512;                                // 512 f32
    unsigned short* hxb  = (unsigned short*)(u_d + 512);   // N*256 u16
    unsigned short* xagg = hxb  + (size_t)N * C1;          // N*512 u16
    unsigned short* xb   = xagg + (size_t)N * 512;         // N*128 u16
    unsigned short* h2b  = xb   + (size_t)N * IN_DIM;      // N*64  u16
    float* a_s1 = (float*)(h2b + (size_t)N * OUT_DIM);     // N*4
    float* a_d1 = a_s1 + (size_t)N * HEADS;                // N*4
    float* a_s2 = a_d1 + (size_t)N * HEADS;                // N
    float* a_d2 = a_s2 + (size_t)N;                        // N
    int* rowptr = (int*)(a_d2 + (size_t)N);                // N+1
    int* cursor = rowptr + (N + 1);                        // N
    int* col    = cursor + N;                              // Etot
    int* psum   = col + Etot;                              // 256

    const size_t needed = (size_t)N * 1968 + (size_t)Etot * 4 + 103428;
    if (ws_size < needed) return;  // loud failure signature

    hipMemsetAsync(rowptr, 0, (size_t)(N + 1) * sizeof(int), stream);

    const int SC    = (N + 255) / 256;           // <=256 chunks (N=50k -> 196)
    const int mblk  = (N + 63) / 64;
    const int nblk4 = (N + 3) / 4;
    const int nchunk = (Etot + 2047) / 2048;     // ~2k edges per chunk
    const int bgrid  = nchunk * 8;               // 8 bins x chunks
    w1f_k   <<<17, 256, 0, stream>>>(W1, as1, ad1, W1f, u_s, u_d);
    w2f_k   <<<8, 256, 0, stream>>>(W2, W2f);
    xprep_k <<<nblk4, 256, 0, stream>>>(x, u_s, u_d, xb, a_s1, a_d1, N);
    deg_k   <<<bgrid, 256, 0, stream>>>(ei, E, Etot, rowptr, N);
    scanA_k <<<SC, 256, 0, stream>>>(rowptr, psum, N);
    scanB_k <<<1, 256, 0, stream>>>(psum, SC);
    scanC_k <<<SC, 256, 0, stream>>>(rowptr, cursor, psum, N);
    fill_k  <<<bgrid, 256, 0, stream>>>(ei, E, Etot, cursor, col, N);
    agg1x_k <<<nblk4, 256, 0, stream>>>(rowptr, col, a_s1, a_d1, xb, xagg, N);
    gemm1b_k<<<mblk, 256, 0, stream>>>(xagg, W1f, b1, hxb, N);
    gemm2_k <<<mblk, 256, 0, stream>>>(hxb, W2f, as2, ad2, h2b, a_s2, a_d2, N);
    agg2_k  <<<nblk4, 256, 0, stream>>>(rowptr, col, a_s2, a_d2, h2b, b2,
                                        (float*)d_out, N);
    dec_k   <<<(N + 31) / 32, 256, 0, stream>>>((const float*)d_out, dW1, db1,
                                                dW2, db2,
                                                (float*)d_out + (size_t)N * OUT_DIM, N);
}